// Round 2
// baseline (8139.944 us; speedup 1.0000x reference)
//
#include <hip/hip_runtime.h>
#include <math.h>

#define EPS_ 1e-5f

static constexpr int Bb = 512, Vv = 4, Tt = 16, Dd = 512, NCc = 174;
static constexpr int NROW = Bb * Vv * Tt;      // 32768
static constexpr int EROW = Bb * 12 * Tt;      // 98304
static constexpr int CB = 64;                  // batches per edge chunk
static constexpr int NCHUNK = Bb / CB;         // 8
static constexpr int CROWS_N = CB * Vv * Tt;   // 4096 node rows per chunk
static constexpr int CROWS_E = CB * 12 * Tt;   // 12288 edge rows per chunk

__constant__ int d_SEND[12] = {0,0,0,1,1,1,2,2,2,3,3,3};
__constant__ int d_RECV[12] = {1,2,3,0,2,3,0,1,3,0,1,2};
__constant__ int d_EOFV[4][3] = {{3,6,9},{0,7,10},{1,4,11},{2,5,8}};

// ---------------- GEMM: C = act( A[M,K] @ W[K,N] + bias + (acc ? C : 0) ) ----
#define BM 64
#define BN 64
#define BK 16

__global__ __launch_bounds__(256) void gemm_k(
    const float* __restrict__ A, const float* __restrict__ W,
    float* __restrict__ C, int M, int N, int K,
    const float* __restrict__ bias, int accflag, int act)
{
    __shared__ float As[BK][BM + 1];
    __shared__ float Bs[BK][BN];
    int tid = threadIdx.x;
    int tx = tid & 15, ty = tid >> 4;
    int rowBase = blockIdx.y * BM;
    int colBase = blockIdx.x * BN;
    float acc[4][4] = {};
    for (int k0 = 0; k0 < K; k0 += BK) {
#pragma unroll
        for (int i = 0; i < 4; ++i) {
            int idx = tid + i * 256;
            int m = idx >> 4, kk = idx & 15;
            int gr = rowBase + m, gk = k0 + kk;
            As[kk][m] = (gr < M && gk < K) ? A[(size_t)gr * K + gk] : 0.f;
        }
#pragma unroll
        for (int i = 0; i < 4; ++i) {
            int idx = tid + i * 256;
            int kk = idx >> 6, n = idx & 63;
            int gk = k0 + kk, gc = colBase + n;
            Bs[kk][n] = (gk < K && gc < N) ? W[(size_t)gk * N + gc] : 0.f;
        }
        __syncthreads();
#pragma unroll
        for (int kk = 0; kk < BK; ++kk) {
            float ra[4], rb[4];
#pragma unroll
            for (int a = 0; a < 4; ++a) ra[a] = As[kk][ty * 4 + a];
#pragma unroll
            for (int b = 0; b < 4; ++b) rb[b] = Bs[kk][tx * 4 + b];
#pragma unroll
            for (int a = 0; a < 4; ++a)
#pragma unroll
                for (int b = 0; b < 4; ++b)
                    acc[a][b] += ra[a] * rb[b];
        }
        __syncthreads();
    }
#pragma unroll
    for (int a = 0; a < 4; ++a) {
        int m = rowBase + ty * 4 + a;
        if (m >= M) continue;
#pragma unroll
        for (int b = 0; b < 4; ++b) {
            int n = colBase + tx * 4 + b;
            if (n >= N) continue;
            float v = acc[a][b];
            if (bias) v += bias[n];
            if (accflag) v += C[(size_t)m * N + n];
            if (act == 1) v = fmaxf(v, 0.f);
            else if (act == 2) v = (v > 0.f) ? v : (expf(v) - 1.f);
            C[(size_t)m * N + n] = v;
        }
    }
}

// ------------- column stats: atomically accumulate sum/sumsq per column -----
__global__ __launch_bounds__(64) void colstats_k(
    const float* __restrict__ X, int R, int C, int rpb, float* __restrict__ slot)
{
    int col = blockIdx.x * 64 + threadIdx.x;
    if (col >= C) return;
    int r0 = blockIdx.y * rpb;
    int r1 = r0 + rpb; if (r1 > R) r1 = R;
    float s = 0.f, sq = 0.f;
    for (int r = r0; r < r1; ++r) {
        float v = X[(size_t)r * C + col];
        s += v; sq += v * v;
    }
    atomicAdd(&slot[col], s);
    atomicAdd(&slot[512 + col], sq);
}

__global__ __launch_bounds__(256) void bn_finalize_k(
    const float* __restrict__ slot, const float* __restrict__ g,
    const float* __restrict__ b, float* __restrict__ sc, int C, float cnt)
{
    int c = blockIdx.x * 256 + threadIdx.x;
    if (c >= C) return;
    float mean = slot[c] / cnt;
    float var = fmaxf(slot[512 + c] / cnt - mean * mean, 0.f);
    float s = g[c] * rsqrtf(var + EPS_);
    sc[c] = s;
    sc[512 + c] = b[c] - mean * s;
}

// X = act( (X*premul)*scale[c] + shift[c] )
__global__ __launch_bounds__(256) void bn_apply_k(
    float* __restrict__ X, long n, int cmask, const float* __restrict__ sc,
    float premul, int act)
{
    long i = (long)blockIdx.x * 256 + threadIdx.x;
    if (i >= n) return;
    int c = (int)(i & cmask);
    float v = X[i] * premul;
    v = v * sc[c] + sc[512 + c];
    if (act == 1) v = fmaxf(v, 0.f);
    else if (act == 2) v = (v > 0.f) ? v : (expf(v) - 1.f);
    X[i] = v;
}

// ---------------- misc elementwise kernels ----------------------------------
__global__ __launch_bounds__(256) void zero_k(float* p, int n)
{
    int i = blockIdx.x * 256 + threadIdx.x;
    if (i < n) p[i] = 0.f;
}

// X0[(b*V+v)*T+t, c] = box[b,t,v,c]
__global__ __launch_bounds__(256) void build_x0_k(
    const float* __restrict__ box, float* __restrict__ X0)
{
    int i = blockIdx.x * 256 + threadIdx.x;
    if (i >= NROW * 4) return;
    int c = i & 3; int r = i >> 2;
    int t = r & 15; int bv = r >> 4; int v = bv & 3; int b = bv >> 2;
    X0[i] = box[(((size_t)b * Tt + t) * Vv + v) * 4 + c];
}

// CE[(b*V+v)*T+t, c] = cat==0 ? 0 : emb[cat, c]   (c < 256)
__global__ __launch_bounds__(256) void build_ce_k(
    const int* __restrict__ cats, const float* __restrict__ emb,
    float* __restrict__ CE)
{
    long i = (long)blockIdx.x * 256 + threadIdx.x;
    if (i >= (long)NROW * 256) return;
    int c = (int)(i & 255); long r = i >> 8;
    int t = (int)(r & 15); int bv = (int)(r >> 4); int v = bv & 3; int b = bv >> 2;
    int cat = cats[((size_t)b * Tt + t) * Vv + v];
    CE[i] = (cat == 0) ? 0.f : emb[cat * 256 + c];
}

// chunk edge gather: E[(brel*12+e)*16+t, c] = elu(P[(brel*4+s)*16+t,c]+Q[..r..,c]+b1[c])
__global__ __launch_bounds__(256) void edge_gather_k(
    const float* __restrict__ P, const float* __restrict__ Q,
    const float* __restrict__ b1, float* __restrict__ E)
{
    int i = blockIdx.x * 256 + threadIdx.x;
    if (i >= CROWS_E * Dd) return;
    int c = i & 511; int m = i >> 9;
    int t = m & 15; int be = m >> 4; int e = be % 12; int brel = be / 12;
    int s = d_SEND[e], r = d_RECV[e];
    float v = P[(((size_t)brel * 4 + s) * 16 + t) * 512 + c]
            + Q[(((size_t)brel * 4 + r) * 16 + t) * 512 + c] + b1[c];
    E[i] = (v > 0.f) ? v : (expf(v) - 1.f);
}

// chunk aggregation: nraw[(b0+brel, v, t), c] = sum over 3 incoming edges
__global__ __launch_bounds__(256) void edge_agg_k(
    const float* __restrict__ E2c, float* __restrict__ nraw, int b0)
{
    int i = blockIdx.x * 256 + threadIdx.x;
    if (i >= CB * Vv * Tt * Dd) return;
    int c = i & 511; int r = i >> 9;
    int t = r & 15; int r2 = r >> 4; int v = r2 & 3; int brel = r2 >> 2;
    float s = 0.f;
#pragma unroll
    for (int j = 0; j < 3; ++j) {
        int e = d_EOFV[v][j];
        s += E2c[(((size_t)brel * 12 + e) * 16 + t) * 512 + c];
    }
    nraw[((((size_t)(b0 + brel)) * 4 + v) * 16 + t) * 512 + c] = s;
}

__global__ __launch_bounds__(256) void feat_mean_k(
    const float* __restrict__ q, float* __restrict__ feat)
{
    int i = blockIdx.x * 256 + threadIdx.x;
    if (i >= Bb * Dd) return;
    int d = i & 511; int b = i >> 9;
    float s = 0.f;
#pragma unroll
    for (int v = 0; v < 4; ++v) s += q[(((size_t)b * 4 + v) << 9) + d];
    feat[i] = 0.25f * s;
}

__global__ __launch_bounds__(256) void copy_labels_k(
    const int* __restrict__ lab, float* __restrict__ out)
{
    int i = blockIdx.x * 256 + threadIdx.x;
    if (i < Bb) out[i] = (float)lab[i];
}

// ---------------- host-side helpers -----------------------------------------
static inline void gemm(hipStream_t s, const float* A, const float* W, float* C,
                        int M, int N, int K, const float* bias, int accf, int act)
{
    dim3 g((N + BN - 1) / BN, (M + BM - 1) / BM);
    hipLaunchKernelGGL(gemm_k, g, dim3(256), 0, s, A, W, C, M, N, K, bias, accf, act);
}

static inline void colstats(hipStream_t s, const float* X, int R, int C, float* slot)
{
    int rpb = 128;
    dim3 g(C / 64, (R + rpb - 1) / rpb);
    hipLaunchKernelGGL(colstats_k, g, dim3(64), 0, s, X, R, C, rpb, slot);
}

static inline void bn_fin(hipStream_t s, const float* slot, const float* g,
                          const float* b, float* sc, int C, float cnt)
{
    hipLaunchKernelGGL(bn_finalize_k, dim3((C + 255) / 256), dim3(256), 0, s,
                       slot, g, b, sc, C, cnt);
}

static inline void bn_apply(hipStream_t s, float* X, long n, int C,
                            const float* sc, float premul, int act)
{
    long nb = (n + 255) / 256;
    hipLaunchKernelGGL(bn_apply_k, dim3((unsigned)nb), dim3(256), 0, s,
                       X, n, C - 1, sc, premul, act);
}

extern "C" void kernel_launch(void* const* d_in, const int* in_sizes, int n_in,
                              void* d_out, int out_size, void* d_ws, size_t ws_size,
                              hipStream_t stream)
{
    const int*   box_cat = (const int*)  d_in[1];
    const float* box_in  = (const float*)d_in[2];
    const int*   vlabel  = (const int*)  d_in[4];
    const float* emb     = (const float*)d_in[5];
    const float* c2f_w1  = (const float*)d_in[6];
    const float* c2f_g1  = (const float*)d_in[7];
    const float* c2f_b1  = (const float*)d_in[8];
    const float* c2f_w2  = (const float*)d_in[9];
    const float* c2f_g2  = (const float*)d_in[10];
    const float* c2f_b2  = (const float*)d_in[11];
    const float* fus_w   = (const float*)d_in[12];
    const float* fus_g   = (const float*)d_in[13];
    const float* fus_b   = (const float*)d_in[14];
    const float* m1_w1   = (const float*)d_in[15];
    const float* m1_b1   = (const float*)d_in[16];
    const float* m1_w2   = (const float*)d_in[17];
    const float* m1_b2   = (const float*)d_in[18];
    const float* m1_g    = (const float*)d_in[19];
    const float* m1_bb   = (const float*)d_in[20];
    const float* m2_w1   = (const float*)d_in[21];
    const float* m2_b1   = (const float*)d_in[22];
    const float* m2_w2   = (const float*)d_in[23];
    const float* m2_b2   = (const float*)d_in[24];
    const float* m2_g    = (const float*)d_in[25];
    const float* m2_bb   = (const float*)d_in[26];
    const float* t1_w1   = (const float*)d_in[27];
    const float* t1_b1   = (const float*)d_in[28];
    const float* t1_w2   = (const float*)d_in[29];
    const float* t1_b2   = (const float*)d_in[30];
    const float* t1_g    = (const float*)d_in[31];
    const float* t1_bb   = (const float*)d_in[32];
    const float* ps_w1   = (const float*)d_in[33];
    const float* ps_g1   = (const float*)d_in[34];
    const float* ps_b1   = (const float*)d_in[35];
    const float* ps_w2   = (const float*)d_in[36];
    const float* ps_g2   = (const float*)d_in[37];
    const float* ps_b2   = (const float*)d_in[38];
    const float* tb_w1   = (const float*)d_in[39];
    const float* tb_g1   = (const float*)d_in[40];
    const float* tb_b1   = (const float*)d_in[41];
    const float* tb_w2   = (const float*)d_in[42];
    const float* tb_g2   = (const float*)d_in[43];
    const float* tb_b2   = (const float*)d_in[44];
    const float* cl_w1   = (const float*)d_in[45];
    const float* cl_b1   = (const float*)d_in[46];
    const float* cl_w2   = (const float*)d_in[47];
    const float* cl_b2   = (const float*)d_in[48];
    const float* cl_w3   = (const float*)d_in[49];
    const float* cl_b3   = (const float*)d_in[50];

    float* out = (float*)d_out;

    // workspace layout (floats): total ~202 MB
    const size_t ND = (size_t)NROW * Dd;          // 16,777,216
    float* ws    = (float*)d_ws;
    float* A0    = ws;                            // 64 MB
    float* A1    = ws + ND;                       // 64 MB
    float* A2    = ws + 2 * ND;                   // 64 MB
    float* X0    = ws + 3 * ND;                   // NROW*4
    float* STATS = X0 + (size_t)NROW * 4;         // 10 slots * 1024
    float* SCALE = STATS + 10 * 1024;             // 10 slots * 1024

    auto slot = [&](int i) { return STATS + (size_t)i * 1024; };
    auto scsh = [&](int i) { return SCALE + (size_t)i * 1024; };

    // sub-buffers inside A2 during prep phase
    float* CE = A2;                               // NROW*256
    float* Y1 = A2 + (size_t)NROW * 256;          // NROW*256
    // sub-buffers inside A2 during edge phase
    float* Pc  = A2;                              // 4096*512
    float* Qc  = A2 + (size_t)CROWS_N * Dd;       // 4096*512
    float* EC1 = Qc + (size_t)CROWS_N * Dd;       // 12288*512
    float* EC2 = EC1 + (size_t)CROWS_E * Dd;      // 12288*512  (ends exactly at A2+ND)

    // 0. zero stats accumulators
    hipLaunchKernelGGL(zero_k, dim3((10 * 1024 + 255) / 256), dim3(256), 0, stream,
                       STATS, 10 * 1024);

    // 1. build X0 and CE
    hipLaunchKernelGGL(build_x0_k, dim3((NROW * 4 + 255) / 256), dim3(256), 0, stream,
                       box_in, X0);
    {
        long n = (long)NROW * 256;
        hipLaunchKernelGGL(build_ce_k, dim3((unsigned)((n + 255) / 256)), dim3(256), 0,
                           stream, box_cat, emb, CE);
    }

    // 2. c2f layer 1: Y1 = relu(BN(X0 @ c2f_w1))   [NROW,256]
    gemm(stream, X0, c2f_w1, Y1, NROW, 256, 4, nullptr, 0, 0);
    colstats(stream, Y1, NROW, 256, slot(0));
    bn_fin(stream, slot(0), c2f_g1, c2f_b1, scsh(0), 256, (float)NROW);
    bn_apply(stream, Y1, (long)NROW * 256, 256, scsh(0), 1.f, 1);

    // 3. c2f layer 2: Y2 = relu(BN(Y1 @ c2f_w2))  [NROW,512] -> A1
    gemm(stream, Y1, c2f_w2, A1, NROW, 512, 256, nullptr, 0, 0);
    colstats(stream, A1, NROW, 512, slot(1));
    bn_fin(stream, slot(1), c2f_g2, c2f_b2, scsh(1), 512, (float)NROW);
    bn_apply(stream, A1, (long)NROW * 512, 512, scsh(1), 1.f, 1);

    // 4. fusion: BF = relu(BN(Y2 @ fus_w[0:512] + CE @ fus_w[512:768])) -> A0
    gemm(stream, A1, fus_w, A0, NROW, 512, 512, nullptr, 0, 0);
    gemm(stream, CE, fus_w + (size_t)512 * 512, A0, NROW, 512, 256, nullptr, 1, 0);
    colstats(stream, A0, NROW, 512, slot(2));
    bn_fin(stream, slot(2), fus_g, fus_b, scsh(2), 512, (float)NROW);
    bn_apply(stream, A0, (long)NROW * 512, 512, scsh(2), 1.f, 1);   // BF in A0

    // 5-7. edge pipeline, chunked over batches; nraw accumulates in A1
    for (int c = 0; c < NCHUNK; ++c) {
        const float* BFc = A0 + (size_t)c * CROWS_N * Dd;
        gemm(stream, BFc, m1_w1, Pc, CROWS_N, 512, 512, nullptr, 0, 0);
        gemm(stream, BFc, m1_w1 + (size_t)512 * 512, Qc, CROWS_N, 512, 512, nullptr, 0, 0);
        hipLaunchKernelGGL(edge_gather_k,
                           dim3((CROWS_E * Dd + 255) / 256), dim3(256), 0, stream,
                           Pc, Qc, m1_b1, EC1);
        gemm(stream, EC1, m1_w2, EC2, CROWS_E, 512, 512, m1_b2, 0, 2);
        colstats(stream, EC2, CROWS_E, 512, slot(3));
        hipLaunchKernelGGL(edge_agg_k,
                           dim3((CB * Vv * Tt * Dd + 255) / 256), dim3(256),
                           0, stream, EC2, A1, c * CB);
    }
    bn_fin(stream, slot(3), m1_g, m1_bb, scsh(3), 512, (float)EROW);
    bn_apply(stream, A1, (long)NROW * 512, 512, scsh(3), 1.f / 3.f, 0); // n in A1

    // 8. m2 MLP: n -> A2 -> A1 (n2)
    gemm(stream, A1, m2_w1, A2, NROW, 512, 512, m2_b1, 0, 2);
    gemm(stream, A2, m2_w2, A1, NROW, 512, 512, m2_b2, 0, 2);
    colstats(stream, A1, NROW, 512, slot(4));
    bn_fin(stream, slot(4), m2_g, m2_bb, scsh(4), 512, (float)NROW);
    bn_apply(stream, A1, (long)NROW * 512, 512, scsh(4), 1.f, 0);    // n2 in A1

    // 9. t1 MLP on cat(n2, BF): -> A2 -> A1 (p)
    gemm(stream, A1, t1_w1, A2, NROW, 512, 512, nullptr, 0, 0);
    gemm(stream, A0, t1_w1 + (size_t)512 * 512, A2, NROW, 512, 512, t1_b1, 1, 2);
    gemm(stream, A2, t1_w2, A1, NROW, 512, 512, t1_b2, 0, 2);
    colstats(stream, A1, NROW, 512, slot(5));
    bn_fin(stream, slot(5), t1_g, t1_bb, scsh(5), 512, (float)NROW);
    bn_apply(stream, A1, (long)NROW * 512, 512, scsh(5), 1.f, 0);    // p in A1

    // 10. ps: two Linear-BN-ReLU; BF (A0) now dead
    gemm(stream, A1, ps_w1, A0, NROW, 512, 512, nullptr, 0, 0);
    colstats(stream, A0, NROW, 512, slot(6));
    bn_fin(stream, slot(6), ps_g1, ps_b1, scsh(6), 512, (float)NROW);
    bn_apply(stream, A0, (long)NROW * 512, 512, scsh(6), 1.f, 1);

    gemm(stream, A0, ps_w2, A1, NROW, 512, 512, nullptr, 0, 0);
    colstats(stream, A1, NROW, 512, slot(7));
    bn_fin(stream, slot(7), ps_g2, ps_b2, scsh(7), 512, (float)NROW);
    bn_apply(stream, A1, (long)NROW * 512, 512, scsh(7), 1.f, 1);    // p_final in A1

    // 11. tb: [2048, 8192] @ tb_w1 -> A2 ; BN-ReLU ; @ tb_w2 -> A0 ; BN-ReLU
    gemm(stream, A1, tb_w1, A2, Bb * Vv, 512, Tt * Dd, nullptr, 0, 0);
    colstats(stream, A2, Bb * Vv, 512, slot(8));
    bn_fin(stream, slot(8), tb_g1, tb_b1, scsh(8), 512, (float)(Bb * Vv));
    bn_apply(stream, A2, (long)Bb * Vv * 512, 512, scsh(8), 1.f, 1);

    gemm(stream, A2, tb_w2, A0, Bb * Vv, 512, 512, nullptr, 0, 0);
    colstats(stream, A0, Bb * Vv, 512, slot(9));
    bn_fin(stream, slot(9), tb_g2, tb_b2, scsh(9), 512, (float)(Bb * Vv));
    bn_apply(stream, A0, (long)Bb * Vv * 512, 512, scsh(9), 1.f, 1); // q2 in A0

    // 12. feat = mean over v -> A1[0 : 512*512]
    hipLaunchKernelGGL(feat_mean_k, dim3((Bb * Dd + 255) / 256), dim3(256), 0, stream,
                       A0, A1);

    // 13. classifier
    float* H1 = A2;
    float* H2 = A1 + (size_t)Bb * Dd;
    gemm(stream, A1, cl_w1, H1, Bb, 512, 512, cl_b1, 0, 1);
    gemm(stream, H1, cl_w2, H2, Bb, 512, 512, cl_b2, 0, 1);
    gemm(stream, H2, cl_w3, out, Bb, NCc, 512, cl_b3, 0, 0);

    // 14. labels
    hipLaunchKernelGGL(copy_labels_k, dim3((Bb + 255) / 256), dim3(256), 0, stream,
                       vlabel, out + (size_t)Bb * NCc);
}

// Round 3
// 2412.267 us; speedup vs baseline: 3.3744x; 3.3744x over previous
//
#include <hip/hip_runtime.h>
#include <math.h>

#define EPS_ 1e-5f

static constexpr int Bb = 512, Vv = 4, Tt = 16, Dd = 512, NCc = 174;
static constexpr int NROW = Bb * Vv * Tt;      // 32768
static constexpr int EROW = Bb * 12 * Tt;      // 98304
static constexpr int CB = 128;                 // batches per edge chunk
static constexpr int NCHUNK = Bb / CB;         // 4
static constexpr int CROWS_N = CB * Vv * Tt;   // 8192
static constexpr int CROWS_E = CB * 12 * Tt;   // 24576

__constant__ int d_SEND[12] = {0,0,0,1,1,1,2,2,2,3,3,3};
__constant__ int d_RECV[12] = {1,2,3,0,2,3,0,1,3,0,1,2};
__constant__ int d_EOFV[4][3] = {{3,6,9},{0,7,10},{1,4,11},{2,5,8}};

typedef float f32x4 __attribute__((ext_vector_type(4)));
typedef short s16x8 __attribute__((ext_vector_type(8)));

static __device__ __forceinline__ float b2f(unsigned short u) {
    union { unsigned int i; float f; } x; x.i = ((unsigned int)u) << 16; return x.f;
}
static __device__ __forceinline__ unsigned short f2b(float f) {
    union { float f; unsigned int i; } x; x.f = f;
    unsigned int r = (x.i + 0x7fffu + ((x.i >> 16) & 1u)) >> 16;
    return (unsigned short)r;
}
static __device__ __forceinline__ float act_f(float v, int act) {
    if (act == 1) return fmaxf(v, 0.f);
    if (act == 2) return (v > 0.f) ? v : (expf(v) - 1.f);
    return v;
}

// ================= MFMA bf16 GEMM =========================================
// C[M,N] = act( A@W + bias ), A bf16 row-major, W given transposed WT[n][k]
// (row stride Kw, k offset wtoff). Dual-input: A0 for k<K0, A1 for K0<=k<K0+K1.
// M % 128 == 0, N % 128 == 0, K0/K1 % 32 == 0.
#define TM 128
#define TN 128
#define LDSS 48  // shorts per LDS row (32 data + 16 pad), 96B (16B aligned)

__global__ __launch_bounds__(256) void gemm_bf16(
    const unsigned short* __restrict__ A0, int Ka0, int K0,
    const unsigned short* __restrict__ A1, int Ka1, int K1,
    const unsigned short* __restrict__ WT, int Kw, int wtoff,
    unsigned short* __restrict__ C, int M, int N,
    const float* __restrict__ bias, int act)
{
    __shared__ unsigned short As[TM * LDSS];
    __shared__ unsigned short Bs[TN * LDSS];
    int tid = threadIdx.x;
    int lane = tid & 63, wave = tid >> 6;
    int wr = wave >> 1, wc = wave & 1;
    int rowBase = blockIdx.y * TM;
    int colBase = blockIdx.x * TN;
    int g = lane >> 4, r16 = lane & 15;

    f32x4 acc[4][4];
#pragma unroll
    for (int i = 0; i < 4; ++i)
#pragma unroll
        for (int j = 0; j < 4; ++j) acc[i][j] = (f32x4){0.f, 0.f, 0.f, 0.f};

    int Ktot = K0 + K1;
    for (int k0 = 0; k0 < Ktot; k0 += 32) {
        const unsigned short* Ap; int lda; int kc;
        if (k0 < K0) { Ap = A0; lda = Ka0; kc = k0; }
        else         { Ap = A1; lda = Ka1; kc = k0 - K0; }
        // stage A: 512 x 16B chunks
#pragma unroll
        for (int it = 0; it < 2; ++it) {
            int c = tid + it * 256;
            int r = c >> 2, sg = c & 3;
            uint4 v = *(const uint4*)(Ap + (size_t)(rowBase + r) * lda + kc + sg * 8);
            *(uint4*)(&As[r * LDSS + sg * 8]) = v;
        }
        // stage B from WT
#pragma unroll
        for (int it = 0; it < 2; ++it) {
            int c = tid + it * 256;
            int r = c >> 2, sg = c & 3;
            uint4 v = *(const uint4*)(WT + (size_t)(colBase + r) * Kw + wtoff + k0 + sg * 8);
            *(uint4*)(&Bs[r * LDSS + sg * 8]) = v;
        }
        __syncthreads();
        s16x8 af[4], bfr[4];
#pragma unroll
        for (int i = 0; i < 4; ++i)
            af[i] = *(const s16x8*)(&As[(i * 16 + wr * 64 + r16) * LDSS + g * 8]);
#pragma unroll
        for (int j = 0; j < 4; ++j)
            bfr[j] = *(const s16x8*)(&Bs[(j * 16 + wc * 64 + r16) * LDSS + g * 8]);
#pragma unroll
        for (int i = 0; i < 4; ++i)
#pragma unroll
            for (int j = 0; j < 4; ++j)
                acc[i][j] = __builtin_amdgcn_mfma_f32_16x16x32_bf16(
                    af[i], bfr[j], acc[i][j], 0, 0, 0);
        __syncthreads();
    }
    // epilogue: D row = (lane>>4)*4 + p, col = lane&15 within each 16x16 tile
#pragma unroll
    for (int j = 0; j < 4; ++j) {
        int col = colBase + wc * 64 + j * 16 + r16;
        float bcol = bias ? bias[col] : 0.f;
#pragma unroll
        for (int i = 0; i < 4; ++i) {
            int row0 = rowBase + wr * 64 + i * 16 + g * 4;
#pragma unroll
            for (int p = 0; p < 4; ++p) {
                float v = acc[i][j][p] + bcol;
                v = act_f(v, act);
                C[(size_t)(row0 + p) * N + col] = f2b(v);
            }
        }
    }
}

// ---- weight convert+transpose: WT[n*K + k] = bf16(W[k*512 + n]), N==512 ----
__global__ __launch_bounds__(256) void transpose_w_k(
    const float* __restrict__ W, unsigned short* __restrict__ WT, int K)
{
    int i = blockIdx.x * 256 + threadIdx.x;
    if (i >= K * 512) return;
    int k = i >> 9, n = i & 511;
    WT[(size_t)n * K + k] = f2b(W[i]);
}

// ---- column stats over bf16 matrix -----------------------------------------
__global__ __launch_bounds__(64) void colstats_k(
    const unsigned short* __restrict__ X, int R, int C, int rpb,
    float* __restrict__ slot)
{
    int col = blockIdx.x * 64 + threadIdx.x;
    if (col >= C) return;
    int r0 = blockIdx.y * rpb;
    int r1 = r0 + rpb; if (r1 > R) r1 = R;
    float s = 0.f, sq = 0.f;
    for (int r = r0; r < r1; ++r) {
        float v = b2f(X[(size_t)r * C + col]);
        s += v; sq += v * v;
    }
    atomicAdd(&slot[col], s);
    atomicAdd(&slot[512 + col], sq);
}

__global__ __launch_bounds__(256) void bn_finalize_k(
    const float* __restrict__ slot, const float* __restrict__ g,
    const float* __restrict__ b, float* __restrict__ sc, int C, float cnt)
{
    int c = blockIdx.x * 256 + threadIdx.x;
    if (c >= C) return;
    float mean = slot[c] / cnt;
    float var = fmaxf(slot[512 + c] / cnt - mean * mean, 0.f);
    float s = g[c] * rsqrtf(var + EPS_);
    sc[c] = s;
    sc[512 + c] = b[c] - mean * s;
}

// in-place: X = act( X*premul*scale[c] + shift[c] ), 4 bf16 per thread
__global__ __launch_bounds__(256) void bn_apply_k(
    unsigned short* __restrict__ X, long n4, int cmask,
    const float* __restrict__ sc, float premul, int act)
{
    long i = (long)blockIdx.x * 256 + threadIdx.x;
    if (i >= n4) return;
    ushort4 x = ((ushort4*)X)[i];
    long cbase = i * 4;
    unsigned short o[4] = {x.x, x.y, x.z, x.w};
#pragma unroll
    for (int e = 0; e < 4; ++e) {
        int c = (int)((cbase + e) & cmask);
        float v = b2f(o[e]) * premul;
        v = v * sc[c] + sc[512 + c];
        o[e] = f2b(act_f(v, act));
    }
    ((ushort4*)X)[i] = make_ushort4(o[0], o[1], o[2], o[3]);
}

// ---------------- misc ------------------------------------------------------
__global__ __launch_bounds__(256) void zero_k(float* p, int n)
{
    int i = blockIdx.x * 256 + threadIdx.x;
    if (i < n) p[i] = 0.f;
}

__global__ __launch_bounds__(256) void build_x0_k(
    const float* __restrict__ box, float* __restrict__ X0)
{
    int i = blockIdx.x * 256 + threadIdx.x;
    if (i >= NROW * 4) return;
    int c = i & 3; int r = i >> 2;
    int t = r & 15; int bv = r >> 4; int v = bv & 3; int b = bv >> 2;
    X0[i] = box[(((size_t)b * Tt + t) * Vv + v) * 4 + c];
}

// CE[(b*V+v)*T+t, c] bf16 ; 4 cols per thread
__global__ __launch_bounds__(256) void build_ce_k(
    const int* __restrict__ cats, const float* __restrict__ emb,
    unsigned short* __restrict__ CE)
{
    int i = blockIdx.x * 256 + threadIdx.x;
    if (i >= NROW * 64) return;
    int c4 = i & 63; int r = i >> 6;
    int t = r & 15; int bv = r >> 4; int v = bv & 3; int b = bv >> 2;
    int cat = cats[((size_t)b * Tt + t) * Vv + v];
    unsigned short o[4];
#pragma unroll
    for (int e = 0; e < 4; ++e)
        o[e] = (cat == 0) ? 0 : f2b(emb[cat * 256 + c4 * 4 + e]);
    ((ushort4*)CE)[(size_t)r * 64 + c4] = make_ushort4(o[0], o[1], o[2], o[3]);
}

// c2f layer-1: Y1[m, n4*4..] = X0f[m,0:4] @ W4[4,256]  (fp32 math, bf16 out)
__global__ __launch_bounds__(256) void smallk_gemm_k(
    const float* __restrict__ X0, const float* __restrict__ W4,
    unsigned short* __restrict__ Y1)
{
    int i = blockIdx.x * 256 + threadIdx.x;
    if (i >= NROW * 64) return;
    int n4 = i & 63; int m = i >> 6;
    float4 x = *(const float4*)(X0 + m * 4);
    unsigned short o[4];
#pragma unroll
    for (int e = 0; e < 4; ++e) {
        int n = n4 * 4 + e;
        float v = x.x * W4[n] + x.y * W4[256 + n] + x.z * W4[512 + n] + x.w * W4[768 + n];
        o[e] = f2b(v);
    }
    ((ushort4*)Y1)[(size_t)m * 64 + n4] = make_ushort4(o[0], o[1], o[2], o[3]);
}

// chunk edge gather (bf16): E[(brel*12+e)*16+t, c] = elu(P[..s..]+Q[..r..]+b1)
__global__ __launch_bounds__(256) void edge_gather_k(
    const unsigned short* __restrict__ P, const unsigned short* __restrict__ Q,
    const float* __restrict__ b1, unsigned short* __restrict__ E)
{
    int i = blockIdx.x * 256 + threadIdx.x;
    if (i >= CROWS_E * 128) return;
    int c4 = i & 127; int m = i >> 7;
    int t = m & 15; int be = m >> 4; int e = be % 12; int brel = be / 12;
    int s = d_SEND[e], r = d_RECV[e];
    ushort4 p = ((const ushort4*)P)[(((size_t)brel * 4 + s) * 16 + t) * 128 + c4];
    ushort4 q = ((const ushort4*)Q)[(((size_t)brel * 4 + r) * 16 + t) * 128 + c4];
    unsigned short pa[4] = {p.x, p.y, p.z, p.w}, qa[4] = {q.x, q.y, q.z, q.w}, o[4];
#pragma unroll
    for (int e2 = 0; e2 < 4; ++e2) {
        float v = b2f(pa[e2]) + b2f(qa[e2]) + b1[c4 * 4 + e2];
        o[e2] = f2b(act_f(v, 2));
    }
    ((ushort4*)E)[i] = make_ushort4(o[0], o[1], o[2], o[3]);
}

// chunk aggregation: nsum[(b0+brel, v, t), c] = sum over 3 incoming edges (bf16)
__global__ __launch_bounds__(256) void edge_agg_k(
    const unsigned short* __restrict__ E2c, unsigned short* __restrict__ nraw, int b0)
{
    int i = blockIdx.x * 256 + threadIdx.x;
    if (i >= CB * Vv * Tt * 128) return;
    int c4 = i & 127; int r = i >> 7;
    int t = r & 15; int r2 = r >> 4; int v = r2 & 3; int brel = r2 >> 2;
    float s[4] = {0.f, 0.f, 0.f, 0.f};
#pragma unroll
    for (int j = 0; j < 3; ++j) {
        int e = d_EOFV[v][j];
        ushort4 x = ((const ushort4*)E2c)[(((size_t)brel * 12 + e) * 16 + t) * 128 + c4];
        s[0] += b2f(x.x); s[1] += b2f(x.y); s[2] += b2f(x.z); s[3] += b2f(x.w);
    }
    ((ushort4*)nraw)[((((size_t)(b0 + brel)) * 4 + v) * 16 + t) * 128 + c4] =
        make_ushort4(f2b(s[0]), f2b(s[1]), f2b(s[2]), f2b(s[3]));
}

__global__ __launch_bounds__(256) void feat_mean_k(
    const unsigned short* __restrict__ q, unsigned short* __restrict__ feat)
{
    int i = blockIdx.x * 256 + threadIdx.x;
    if (i >= Bb * 128) return;
    int c4 = i & 127; int b = i >> 7;
    float s[4] = {0.f, 0.f, 0.f, 0.f};
#pragma unroll
    for (int v = 0; v < 4; ++v) {
        ushort4 x = ((const ushort4*)q)[(((size_t)b * 4 + v)) * 128 + c4];
        s[0] += b2f(x.x); s[1] += b2f(x.y); s[2] += b2f(x.z); s[3] += b2f(x.w);
    }
    ((ushort4*)feat)[(size_t)b * 128 + c4] = make_ushort4(
        f2b(0.25f * s[0]), f2b(0.25f * s[1]), f2b(0.25f * s[2]), f2b(0.25f * s[3]));
}

// final: out[m,n] = bf16 H2[m,:] @ fp32 cl_w3[:,n] + b3[n]
__global__ __launch_bounds__(256) void final_gemm_k(
    const unsigned short* __restrict__ H2, const float* __restrict__ W,
    const float* __restrict__ b, float* __restrict__ out)
{
    int i = blockIdx.x * 256 + threadIdx.x;
    if (i >= Bb * NCc) return;
    int n = i % NCc; int m = i / NCc;
    float s = b[n];
    for (int k = 0; k < 512; ++k)
        s += b2f(H2[(size_t)m * 512 + k]) * W[(size_t)k * NCc + n];
    out[i] = s;
}

__global__ __launch_bounds__(256) void copy_labels_k(
    const int* __restrict__ lab, float* __restrict__ out)
{
    int i = blockIdx.x * 256 + threadIdx.x;
    if (i < Bb) out[i] = (float)lab[i];
}

// ---------------- host-side helpers -----------------------------------------
static inline void gemm(hipStream_t s,
                        const unsigned short* A0, int Ka0, int K0,
                        const unsigned short* A1, int Ka1, int K1,
                        const unsigned short* WT, int Kw, int wtoff,
                        unsigned short* C, int M, int N,
                        const float* bias, int act)
{
    dim3 g(N / TN, M / TM);
    hipLaunchKernelGGL(gemm_bf16, g, dim3(256), 0, s,
                       A0, Ka0, K0, A1, Ka1, K1, WT, Kw, wtoff, C, M, N, bias, act);
}

static inline void colstats(hipStream_t s, const unsigned short* X, int R, int C,
                            float* slot)
{
    int rpb = 256;
    dim3 g(C / 64, (R + rpb - 1) / rpb);
    hipLaunchKernelGGL(colstats_k, g, dim3(64), 0, s, X, R, C, rpb, slot);
}

static inline void bn_fin(hipStream_t s, const float* slot, const float* g,
                          const float* b, float* sc, int C, float cnt)
{
    hipLaunchKernelGGL(bn_finalize_k, dim3((C + 255) / 256), dim3(256), 0, s,
                       slot, g, b, sc, C, cnt);
}

static inline void bn_apply(hipStream_t s, unsigned short* X, long n, int C,
                            const float* sc, float premul, int act)
{
    long n4 = n / 4;
    hipLaunchKernelGGL(bn_apply_k, dim3((unsigned)((n4 + 255) / 256)), dim3(256), 0, s,
                       X, n4, C - 1, sc, premul, act);
}

static inline void transposeW(hipStream_t s, const float* W, unsigned short* WT, int K)
{
    int n = K * 512;
    hipLaunchKernelGGL(transpose_w_k, dim3((n + 255) / 256), dim3(256), 0, s, W, WT, K);
}

extern "C" void kernel_launch(void* const* d_in, const int* in_sizes, int n_in,
                              void* d_out, int out_size, void* d_ws, size_t ws_size,
                              hipStream_t stream)
{
    const int*   box_cat = (const int*)  d_in[1];
    const float* box_in  = (const float*)d_in[2];
    const int*   vlabel  = (const int*)  d_in[4];
    const float* emb     = (const float*)d_in[5];
    const float* c2f_w1  = (const float*)d_in[6];
    const float* c2f_g1  = (const float*)d_in[7];
    const float* c2f_b1  = (const float*)d_in[8];
    const float* c2f_w2  = (const float*)d_in[9];
    const float* c2f_g2  = (const float*)d_in[10];
    const float* c2f_b2  = (const float*)d_in[11];
    const float* fus_w   = (const float*)d_in[12];
    const float* fus_g   = (const float*)d_in[13];
    const float* fus_b   = (const float*)d_in[14];
    const float* m1_w1   = (const float*)d_in[15];
    const float* m1_b1   = (const float*)d_in[16];
    const float* m1_w2   = (const float*)d_in[17];
    const float* m1_b2   = (const float*)d_in[18];
    const float* m1_g    = (const float*)d_in[19];
    const float* m1_bb   = (const float*)d_in[20];
    const float* m2_w1   = (const float*)d_in[21];
    const float* m2_b1   = (const float*)d_in[22];
    const float* m2_w2   = (const float*)d_in[23];
    const float* m2_b2   = (const float*)d_in[24];
    const float* m2_g    = (const float*)d_in[25];
    const float* m2_bb   = (const float*)d_in[26];
    const float* t1_w1   = (const float*)d_in[27];
    const float* t1_b1   = (const float*)d_in[28];
    const float* t1_w2   = (const float*)d_in[29];
    const float* t1_b2   = (const float*)d_in[30];
    const float* t1_g    = (const float*)d_in[31];
    const float* t1_bb   = (const float*)d_in[32];
    const float* ps_w1   = (const float*)d_in[33];
    const float* ps_g1   = (const float*)d_in[34];
    const float* ps_b1   = (const float*)d_in[35];
    const float* ps_w2   = (const float*)d_in[36];
    const float* ps_g2   = (const float*)d_in[37];
    const float* ps_b2   = (const float*)d_in[38];
    const float* tb_w1   = (const float*)d_in[39];
    const float* tb_g1   = (const float*)d_in[40];
    const float* tb_b1   = (const float*)d_in[41];
    const float* tb_w2   = (const float*)d_in[42];
    const float* tb_g2   = (const float*)d_in[43];
    const float* tb_b2   = (const float*)d_in[44];
    const float* cl_w1   = (const float*)d_in[45];
    const float* cl_b1   = (const float*)d_in[46];
    const float* cl_w2   = (const float*)d_in[47];
    const float* cl_b2   = (const float*)d_in[48];
    const float* cl_w3   = (const float*)d_in[49];
    const float* cl_b3   = (const float*)d_in[50];

    float* out = (float*)d_out;

    // ---------------- workspace layout (bytes) ------------------------------
    char* base = (char*)d_ws;
    const size_t SZ_ACT = (size_t)NROW * 512 * 2;       // 32 MB
    unsigned short* A0v = (unsigned short*)(base);
    unsigned short* A1v = (unsigned short*)(base + SZ_ACT);
    char* Sreg = base + 2 * SZ_ACT;                     // 64 MB scratch region
    unsigned short* A2v = (unsigned short*)Sreg;        // 32 MB window in S
    // prep-phase aliases in S
    unsigned short* CE  = (unsigned short*)Sreg;                       // 16 MB
    unsigned short* Y1  = (unsigned short*)(Sreg + (size_t)NROW * 256 * 2);
    // edge-phase aliases in S
    unsigned short* Pc  = (unsigned short*)Sreg;                                   // 8 MB
    unsigned short* Qc  = (unsigned short*)(Sreg + (size_t)CROWS_N * 512 * 2);     // 8 MB
    unsigned short* EC1 = (unsigned short*)(Sreg + 2 * (size_t)CROWS_N * 512 * 2); // 24 MB
    unsigned short* EC2 = (unsigned short*)(Sreg + 2 * (size_t)CROWS_N * 512 * 2
                                                 + (size_t)CROWS_E * 512 * 2);     // 24 MB
    char* wtb = Sreg + 2 * (size_t)CROWS_N * 512 * 2 + 2 * (size_t)CROWS_E * 512 * 2;
    // WT region
    unsigned short* wtp = (unsigned short*)wtb;
    size_t wo = 0;
    auto alloc_wt = [&](int K) { unsigned short* p = wtp + wo; wo += (size_t)K * 512; return p; };
    unsigned short* WTc2f2 = alloc_wt(256);
    unsigned short* WTfus  = alloc_wt(768);
    unsigned short* WTm1a  = alloc_wt(1024);
    unsigned short* WTm1b  = alloc_wt(512);
    unsigned short* WTm2a  = alloc_wt(512);
    unsigned short* WTm2b  = alloc_wt(512);
    unsigned short* WTt1a  = alloc_wt(1024);
    unsigned short* WTt1b  = alloc_wt(512);
    unsigned short* WTps1  = alloc_wt(512);
    unsigned short* WTps2  = alloc_wt(512);
    unsigned short* WTtb1  = alloc_wt(8192);
    unsigned short* WTtb2  = alloc_wt(512);
    unsigned short* WTcl1  = alloc_wt(512);
    unsigned short* WTcl2  = alloc_wt(512);
    float* X0f   = (float*)(wtp + wo);
    float* STATS = X0f + (size_t)NROW * 4;
    float* SCALE = STATS + 10 * 1024;

    auto slot = [&](int i) { return STATS + (size_t)i * 1024; };
    auto scsh = [&](int i) { return SCALE + (size_t)i * 1024; };

    // 0. zero stats + weight prep
    hipLaunchKernelGGL(zero_k, dim3((10 * 1024 + 255) / 256), dim3(256), 0, stream,
                       STATS, 10 * 1024);
    transposeW(stream, c2f_w2, WTc2f2, 256);
    transposeW(stream, fus_w,  WTfus,  768);
    transposeW(stream, m1_w1,  WTm1a,  1024);
    transposeW(stream, m1_w2,  WTm1b,  512);
    transposeW(stream, m2_w1,  WTm2a,  512);
    transposeW(stream, m2_w2,  WTm2b,  512);
    transposeW(stream, t1_w1,  WTt1a,  1024);
    transposeW(stream, t1_w2,  WTt1b,  512);
    transposeW(stream, ps_w1,  WTps1,  512);
    transposeW(stream, ps_w2,  WTps2,  512);
    transposeW(stream, tb_w1,  WTtb1,  8192);
    transposeW(stream, tb_w2,  WTtb2,  512);
    transposeW(stream, cl_w1,  WTcl1,  512);
    transposeW(stream, cl_w2,  WTcl2,  512);

    // 1. inputs
    hipLaunchKernelGGL(build_x0_k, dim3((NROW * 4 + 255) / 256), dim3(256), 0, stream,
                       box_in, X0f);
    hipLaunchKernelGGL(build_ce_k, dim3((NROW * 64 + 255) / 256), dim3(256), 0, stream,
                       box_cat, emb, CE);

    // 2. c2f layer 1 (K=4 fp32) -> Y1 [NROW,256]; BN+ReLU in place
    hipLaunchKernelGGL(smallk_gemm_k, dim3((NROW * 64 + 255) / 256), dim3(256), 0,
                       stream, X0f, c2f_w1, Y1);
    colstats(stream, Y1, NROW, 256, slot(0));
    bn_fin(stream, slot(0), c2f_g1, c2f_b1, scsh(0), 256, (float)NROW);
    bn_apply(stream, Y1, (long)NROW * 256, 256, scsh(0), 1.f, 1);

    // 3. c2f layer 2 -> A1; BN+ReLU
    gemm(stream, Y1, 256, 256, nullptr, 0, 0, WTc2f2, 256, 0, A1v, NROW, 512, nullptr, 0);
    colstats(stream, A1v, NROW, 512, slot(1));
    bn_fin(stream, slot(1), c2f_g2, c2f_b2, scsh(1), 512, (float)NROW);
    bn_apply(stream, A1v, (long)NROW * 512, 512, scsh(1), 1.f, 1);

    // 4. fusion dual-K -> A0 (BF); BN+ReLU
    gemm(stream, A1v, 512, 512, CE, 256, 256, WTfus, 768, 0, A0v, NROW, 512, nullptr, 0);
    colstats(stream, A0v, NROW, 512, slot(2));
    bn_fin(stream, slot(2), fus_g, fus_b, scsh(2), 512, (float)NROW);
    bn_apply(stream, A0v, (long)NROW * 512, 512, scsh(2), 1.f, 1);   // BF in A0

    // 5-7. edge pipeline chunked; node sums -> A1
    for (int c = 0; c < NCHUNK; ++c) {
        const unsigned short* BFc = A0v + (size_t)c * CROWS_N * 512;
        gemm(stream, BFc, 512, 512, nullptr, 0, 0, WTm1a, 1024, 0,   Pc, CROWS_N, 512, nullptr, 0);
        gemm(stream, BFc, 512, 512, nullptr, 0, 0, WTm1a, 1024, 512, Qc, CROWS_N, 512, nullptr, 0);
        hipLaunchKernelGGL(edge_gather_k, dim3((CROWS_E * 128 + 255) / 256), dim3(256),
                           0, stream, Pc, Qc, m1_b1, EC1);
        gemm(stream, EC1, 512, 512, nullptr, 0, 0, WTm1b, 512, 0, EC2, CROWS_E, 512,
             m1_b2, 2);
        colstats(stream, EC2, CROWS_E, 512, slot(3));
        hipLaunchKernelGGL(edge_agg_k, dim3((CB * Vv * Tt * 128 + 255) / 256), dim3(256),
                           0, stream, EC2, A1v, c * CB);
    }
    bn_fin(stream, slot(3), m1_g, m1_bb, scsh(3), 512, (float)EROW);
    bn_apply(stream, A1v, (long)NROW * 512, 512, scsh(3), 1.f / 3.f, 0); // n in A1

    // 8. m2 MLP
    gemm(stream, A1v, 512, 512, nullptr, 0, 0, WTm2a, 512, 0, A2v, NROW, 512, m2_b1, 2);
    gemm(stream, A2v, 512, 512, nullptr, 0, 0, WTm2b, 512, 0, A1v, NROW, 512, m2_b2, 2);
    colstats(stream, A1v, NROW, 512, slot(4));
    bn_fin(stream, slot(4), m2_g, m2_bb, scsh(4), 512, (float)NROW);
    bn_apply(stream, A1v, (long)NROW * 512, 512, scsh(4), 1.f, 0);   // n2 in A1

    // 9. t1 MLP on cat(n2, BF)
    gemm(stream, A1v, 512, 512, A0v, 512, 512, WTt1a, 1024, 0, A2v, NROW, 512, t1_b1, 2);
    gemm(stream, A2v, 512, 512, nullptr, 0, 0, WTt1b, 512, 0, A1v, NROW, 512, t1_b2, 2);
    colstats(stream, A1v, NROW, 512, slot(5));
    bn_fin(stream, slot(5), t1_g, t1_bb, scsh(5), 512, (float)NROW);
    bn_apply(stream, A1v, (long)NROW * 512, 512, scsh(5), 1.f, 0);   // p in A1

    // 10. ps
    gemm(stream, A1v, 512, 512, nullptr, 0, 0, WTps1, 512, 0, A2v, NROW, 512, nullptr, 0);
    colstats(stream, A2v, NROW, 512, slot(6));
    bn_fin(stream, slot(6), ps_g1, ps_b1, scsh(6), 512, (float)NROW);
    bn_apply(stream, A2v, (long)NROW * 512, 512, scsh(6), 1.f, 1);

    gemm(stream, A2v, 512, 512, nullptr, 0, 0, WTps2, 512, 0, A0v, NROW, 512, nullptr, 0);
    colstats(stream, A0v, NROW, 512, slot(7));
    bn_fin(stream, slot(7), ps_g2, ps_b2, scsh(7), 512, (float)NROW);
    bn_apply(stream, A0v, (long)NROW * 512, 512, scsh(7), 1.f, 1);   // p_final in A0

    // 11. tb (A0 viewed [2048 x 8192])
    gemm(stream, A0v, 8192, 8192, nullptr, 0, 0, WTtb1, 8192, 0, A1v, Bb * Vv, 512,
         nullptr, 0);
    colstats(stream, A1v, Bb * Vv, 512, slot(8));
    bn_fin(stream, slot(8), tb_g1, tb_b1, scsh(8), 512, (float)(Bb * Vv));
    bn_apply(stream, A1v, (long)Bb * Vv * 512, 512, scsh(8), 1.f, 1);

    gemm(stream, A1v, 512, 512, nullptr, 0, 0, WTtb2, 512, 0, A2v, Bb * Vv, 512,
         nullptr, 0);
    colstats(stream, A2v, Bb * Vv, 512, slot(9));
    bn_fin(stream, slot(9), tb_g2, tb_b2, scsh(9), 512, (float)(Bb * Vv));
    bn_apply(stream, A2v, (long)Bb * Vv * 512, 512, scsh(9), 1.f, 1); // q2 in A2

    // 12. feat mean -> A0 (512x512)
    hipLaunchKernelGGL(feat_mean_k, dim3((Bb * 128 + 255) / 256), dim3(256), 0, stream,
                       A2v, A0v);

    // 13. classifier
    gemm(stream, A0v, 512, 512, nullptr, 0, 0, WTcl1, 512, 0, A1v, Bb, 512, cl_b1, 1);
    gemm(stream, A1v, 512, 512, nullptr, 0, 0, WTcl2, 512, 0, A2v, Bb, 512, cl_b2, 1);
    hipLaunchKernelGGL(final_gemm_k, dim3((Bb * NCc + 255) / 256), dim3(256), 0, stream,
                       A2v, cl_w3, cl_b3, out);

    // 14. labels
    hipLaunchKernelGGL(copy_labels_k, dim3((Bb + 255) / 256), dim3(256), 0, stream,
                       vlabel, out + (size_t)Bb * NCc);
}

// Round 4
// 1759.559 us; speedup vs baseline: 4.6261x; 1.3709x over previous
//
#include <hip/hip_runtime.h>
#include <math.h>

#define EPS_ 1e-5f

static constexpr int Bb = 512, Vv = 4, Tt = 16, Dd = 512, NCc = 174;
static constexpr int NROW = Bb * Vv * Tt;      // 32768
static constexpr int EROW = Bb * 12 * Tt;      // 98304
static constexpr int CB = 128;                 // batches per edge chunk
static constexpr int NCHUNK = Bb / CB;         // 4
static constexpr int CROWS_N = CB * Vv * Tt;   // 8192
static constexpr int CROWS_E = CB * 12 * Tt;   // 24576

__constant__ int d_SEND[12] = {0,0,0,1,1,1,2,2,2,3,3,3};
__constant__ int d_RECV[12] = {1,2,3,0,2,3,0,1,3,0,1,2};
__constant__ int d_EOFV[4][3] = {{3,6,9},{0,7,10},{1,4,11},{2,5,8}};

typedef float f32x4 __attribute__((ext_vector_type(4)));
typedef short s16x8 __attribute__((ext_vector_type(8)));

static __device__ __forceinline__ float b2f(unsigned short u) {
    union { unsigned int i; float f; } x; x.i = ((unsigned int)u) << 16; return x.f;
}
static __device__ __forceinline__ unsigned short f2b(float f) {
    union { float f; unsigned int i; } x; x.f = f;
    unsigned int r = (x.i + 0x7fffu + ((x.i >> 16) & 1u)) >> 16;
    return (unsigned short)r;
}
static __device__ __forceinline__ float act_f(float v, int act) {
    if (act == 1) return fmaxf(v, 0.f);
    if (act == 2) return (v > 0.f) ? v : (expf(v) - 1.f);
    return v;
}

#define GL2LDS(g, l) __builtin_amdgcn_global_load_lds(                     \
    (__attribute__((address_space(1))) void*)(g),                          \
    (__attribute__((address_space(3))) void*)(l), 16, 0, 0)

// ================= MFMA bf16 GEMM (m97-style global_load_lds staging) =====
// C[M,N] = act( A@W + bias ), A bf16 row-major, W transposed WT[n][k]
// (row stride Kw, k offset wtoff). Dual-input A: k<K0 from A0, else A1.
// Fused column stats (sum/sumsq of the WRITTEN value) when stats!=nullptr.
// Split-K: grid.z slices of Ksl; fp32 partials to Cpart[z][M][N] (no act/stats).
// M,N % 128 == 0; K0,K1,Ksl % 32 == 0.
__global__ __launch_bounds__(256) void gemm_bf16(
    const unsigned short* __restrict__ A0, int Ka0, int K0,
    const unsigned short* __restrict__ A1, int Ka1, int K1,
    const unsigned short* __restrict__ WT, int Kw, int wtoff,
    unsigned short* __restrict__ C, int M, int N,
    const float* __restrict__ bias, int act,
    float* __restrict__ stats, float* __restrict__ Cpart, int Ksl)
{
    __shared__ __align__(16) unsigned short As[128 * 32];
    __shared__ __align__(16) unsigned short Bs[128 * 32];
    int tid = threadIdx.x;
    int lane = tid & 63, wave = tid >> 6;
    int wr = wave >> 1, wc = wave & 1;
    int rowBase = blockIdx.y * 128;
    int colBase = blockIdx.x * 128;
    int g = lane >> 4, r16 = lane & 15;
    int koff = blockIdx.z * Ksl;

    // staging geometry: each wave stages rows [wave*32, wave*32+32) of each tile;
    // one global_load_lds moves 64 lanes x 16B = 16 rows of 64B (32 bf16).
    int srow = wave * 32 + (lane >> 2);   // wave*32 .. wave*32+15
    int scol = (lane & 3) * 8;            // 0,8,16,24 (bf16 elems)
    unsigned short* lA0 = As + (wave * 32) * 32;
    unsigned short* lA1 = As + (wave * 32 + 16) * 32;
    unsigned short* lB0 = Bs + (wave * 32) * 32;
    unsigned short* lB1 = Bs + (wave * 32 + 16) * 32;
    const unsigned short* wrow  = WT + (size_t)(colBase + srow) * Kw + wtoff + scol;
    const unsigned short* wrow2 = WT + (size_t)(colBase + srow + 16) * Kw + wtoff + scol;

    f32x4 acc[4][4];
#pragma unroll
    for (int i = 0; i < 4; ++i)
#pragma unroll
        for (int j = 0; j < 4; ++j) acc[i][j] = (f32x4){0.f, 0.f, 0.f, 0.f};

    for (int k0 = 0; k0 < Ksl; k0 += 32) {
        int kg = koff + k0;
        const unsigned short* Ap; int lda; int kc;
        if (kg < K0) { Ap = A0; lda = Ka0; kc = kg; }
        else         { Ap = A1; lda = Ka1; kc = kg - K0; }
        const unsigned short* ga = Ap + (size_t)(rowBase + srow) * lda + kc + scol;
        GL2LDS(ga, lA0);
        GL2LDS(ga + (size_t)16 * lda, lA1);
        GL2LDS(wrow + kg, lB0);
        GL2LDS(wrow2 + kg, lB1);
        __syncthreads();
        s16x8 af[4], bfv[4];
#pragma unroll
        for (int i = 0; i < 4; ++i)
            af[i] = *(const s16x8*)(As + (wr * 64 + i * 16 + r16) * 32 + g * 8);
#pragma unroll
        for (int j = 0; j < 4; ++j)
            bfv[j] = *(const s16x8*)(Bs + (wc * 64 + j * 16 + r16) * 32 + g * 8);
#pragma unroll
        for (int i = 0; i < 4; ++i)
#pragma unroll
            for (int j = 0; j < 4; ++j)
                acc[i][j] = __builtin_amdgcn_mfma_f32_16x16x32_bf16(
                    af[i], bfv[j], acc[i][j], 0, 0, 0);
        __syncthreads();
    }

    if (Cpart) {
        // split-K partial: raw fp32, no bias/act/stats
#pragma unroll
        for (int j = 0; j < 4; ++j) {
            int col = colBase + wc * 64 + j * 16 + r16;
#pragma unroll
            for (int i = 0; i < 4; ++i) {
                int row0 = rowBase + wr * 64 + i * 16 + g * 4;
#pragma unroll
                for (int p = 0; p < 4; ++p)
                    Cpart[((size_t)blockIdx.z * M + row0 + p) * N + col] = acc[i][j][p];
            }
        }
        return;
    }

#pragma unroll
    for (int j = 0; j < 4; ++j) {
        int col = colBase + wc * 64 + j * 16 + r16;
        float bcol = bias ? bias[col] : 0.f;
        float ssum = 0.f, sqsum = 0.f;
#pragma unroll
        for (int i = 0; i < 4; ++i) {
            int row0 = rowBase + wr * 64 + i * 16 + g * 4;
#pragma unroll
            for (int p = 0; p < 4; ++p) {
                float v = acc[i][j][p] + bcol;
                v = act_f(v, act);
                C[(size_t)(row0 + p) * N + col] = f2b(v);
                ssum += v; sqsum += v * v;
            }
        }
        if (stats) {
            ssum  += __shfl_xor(ssum, 16);  ssum  += __shfl_xor(ssum, 32);
            sqsum += __shfl_xor(sqsum, 16); sqsum += __shfl_xor(sqsum, 32);
            if (g == 0) {
                atomicAdd(&stats[col], ssum);
                atomicAdd(&stats[512 + col], sqsum);
            }
        }
    }
}

// ---- split-K combine: C = act(sum_z P[z]), fused stats ---------------------
__global__ __launch_bounds__(256) void combine_k(
    const float* __restrict__ P, int S, int M, int N,
    unsigned short* __restrict__ C, float* __restrict__ stats, int act)
{
    int col = blockIdx.x * 128 + (threadIdx.x & 127);
    int half = threadIdx.x >> 7;
    int rowBase = blockIdx.y * 128;
    float s = 0.f, sq = 0.f;
    for (int it = 0; it < 64; ++it) {
        int row = rowBase + it * 2 + half;
        float v = 0.f;
        for (int z = 0; z < S; ++z)
            v += P[((size_t)z * M + row) * N + col];
        v = act_f(v, act);
        C[(size_t)row * N + col] = f2b(v);
        s += v; sq += v * v;
    }
    __shared__ float sb[256], qb[256];
    sb[threadIdx.x] = s; qb[threadIdx.x] = sq;
    __syncthreads();
    if (threadIdx.x < 128) {
        atomicAdd(&stats[col], sb[threadIdx.x] + sb[threadIdx.x + 128]);
        atomicAdd(&stats[512 + col], qb[threadIdx.x] + qb[threadIdx.x + 128]);
    }
}

// ---- weight convert+transpose: WT[n*K + k] = bf16(W[k*512 + n]), N==512 ----
__global__ __launch_bounds__(256) void transpose_w_k(
    const float* __restrict__ W, unsigned short* __restrict__ WT, int K)
{
    int i = blockIdx.x * 256 + threadIdx.x;
    if (i >= K * 512) return;
    int k = i >> 9, n = i & 511;
    WT[(size_t)n * K + k] = f2b(W[i]);
}

// ---- column stats over bf16 matrix (only for the K=4 first layer) ----------
__global__ __launch_bounds__(64) void colstats_k(
    const unsigned short* __restrict__ X, int R, int C, int rpb,
    float* __restrict__ slot)
{
    int col = blockIdx.x * 64 + threadIdx.x;
    if (col >= C) return;
    int r0 = blockIdx.y * rpb;
    int r1 = r0 + rpb; if (r1 > R) r1 = R;
    float s = 0.f, sq = 0.f;
    for (int r = r0; r < r1; ++r) {
        float v = b2f(X[(size_t)r * C + col]);
        s += v; sq += v * v;
    }
    atomicAdd(&slot[col], s);
    atomicAdd(&slot[512 + col], sq);
}

__global__ __launch_bounds__(256) void bn_finalize_k(
    const float* __restrict__ slot, const float* __restrict__ g,
    const float* __restrict__ b, float* __restrict__ sc, int C, float cnt)
{
    int c = blockIdx.x * 256 + threadIdx.x;
    if (c >= C) return;
    float mean = slot[c] / cnt;
    float var = fmaxf(slot[512 + c] / cnt - mean * mean, 0.f);
    float s = g[c] * rsqrtf(var + EPS_);
    sc[c] = s;
    sc[512 + c] = b[c] - mean * s;
}

// in-place: X = act( X*premul*scale[c] + shift[c] ), 4 bf16 per thread
__global__ __launch_bounds__(256) void bn_apply_k(
    unsigned short* __restrict__ X, long n4, int cmask,
    const float* __restrict__ sc, float premul, int act)
{
    long i = (long)blockIdx.x * 256 + threadIdx.x;
    if (i >= n4) return;
    ushort4 x = ((ushort4*)X)[i];
    long cbase = i * 4;
    unsigned short o[4] = {x.x, x.y, x.z, x.w};
#pragma unroll
    for (int e = 0; e < 4; ++e) {
        int c = (int)((cbase + e) & cmask);
        float v = b2f(o[e]) * premul;
        v = v * sc[c] + sc[512 + c];
        o[e] = f2b(act_f(v, act));
    }
    ((ushort4*)X)[i] = make_ushort4(o[0], o[1], o[2], o[3]);
}

// ---------------- misc ------------------------------------------------------
__global__ __launch_bounds__(256) void zero_k(float* p, int n)
{
    int i = blockIdx.x * 256 + threadIdx.x;
    if (i < n) p[i] = 0.f;
}

__global__ __launch_bounds__(256) void build_x0_k(
    const float* __restrict__ box, float* __restrict__ X0)
{
    int i = blockIdx.x * 256 + threadIdx.x;
    if (i >= NROW * 4) return;
    int c = i & 3; int r = i >> 2;
    int t = r & 15; int bv = r >> 4; int v = bv & 3; int b = bv >> 2;
    X0[i] = box[(((size_t)b * Tt + t) * Vv + v) * 4 + c];
}

// CE[(b*V+v)*T+t, c] bf16 ; 4 cols per thread
__global__ __launch_bounds__(256) void build_ce_k(
    const int* __restrict__ cats, const float* __restrict__ emb,
    unsigned short* __restrict__ CE)
{
    int i = blockIdx.x * 256 + threadIdx.x;
    if (i >= NROW * 64) return;
    int c4 = i & 63; int r = i >> 6;
    int t = r & 15; int bv = r >> 4; int v = bv & 3; int b = bv >> 2;
    int cat = cats[((size_t)b * Tt + t) * Vv + v];
    unsigned short o[4];
#pragma unroll
    for (int e = 0; e < 4; ++e)
        o[e] = (cat == 0) ? 0 : f2b(emb[cat * 256 + c4 * 4 + e]);
    ((ushort4*)CE)[(size_t)r * 64 + c4] = make_ushort4(o[0], o[1], o[2], o[3]);
}

// c2f layer-1: Y1[m, n4*4..] = X0f[m,0:4] @ W4[4,256]  (fp32 math, bf16 out)
__global__ __launch_bounds__(256) void smallk_gemm_k(
    const float* __restrict__ X0, const float* __restrict__ W4,
    unsigned short* __restrict__ Y1)
{
    int i = blockIdx.x * 256 + threadIdx.x;
    if (i >= NROW * 64) return;
    int n4 = i & 63; int m = i >> 6;
    float4 x = *(const float4*)(X0 + m * 4);
    unsigned short o[4];
#pragma unroll
    for (int e = 0; e < 4; ++e) {
        int n = n4 * 4 + e;
        float v = x.x * W4[n] + x.y * W4[256 + n] + x.z * W4[512 + n] + x.w * W4[768 + n];
        o[e] = f2b(v);
    }
    ((ushort4*)Y1)[(size_t)m * 64 + n4] = make_ushort4(o[0], o[1], o[2], o[3]);
}

// chunk edge gather (bf16): E[(brel*12+e)*16+t, c] = elu(P[..s..]+Q[..r..]+b1)
__global__ __launch_bounds__(256) void edge_gather_k(
    const unsigned short* __restrict__ P, const unsigned short* __restrict__ Q,
    const float* __restrict__ b1, unsigned short* __restrict__ E)
{
    int i = blockIdx.x * 256 + threadIdx.x;
    if (i >= CROWS_E * 128) return;
    int c4 = i & 127; int m = i >> 7;
    int t = m & 15; int be = m >> 4; int e = be % 12; int brel = be / 12;
    int s = d_SEND[e], r = d_RECV[e];
    ushort4 p = ((const ushort4*)P)[(((size_t)brel * 4 + s) * 16 + t) * 128 + c4];
    ushort4 q = ((const ushort4*)Q)[(((size_t)brel * 4 + r) * 16 + t) * 128 + c4];
    unsigned short pa[4] = {p.x, p.y, p.z, p.w}, qa[4] = {q.x, q.y, q.z, q.w}, o[4];
#pragma unroll
    for (int e2 = 0; e2 < 4; ++e2) {
        float v = b2f(pa[e2]) + b2f(qa[e2]) + b1[c4 * 4 + e2];
        o[e2] = f2b(act_f(v, 2));
    }
    ((ushort4*)E)[i] = make_ushort4(o[0], o[1], o[2], o[3]);
}

// chunk aggregation: nsum[(b0+brel, v, t), c] = sum over 3 incoming edges (bf16)
__global__ __launch_bounds__(256) void edge_agg_k(
    const unsigned short* __restrict__ E2c, unsigned short* __restrict__ nraw, int b0)
{
    int i = blockIdx.x * 256 + threadIdx.x;
    if (i >= CB * Vv * Tt * 128) return;
    int c4 = i & 127; int r = i >> 7;
    int t = r & 15; int r2 = r >> 4; int v = r2 & 3; int brel = r2 >> 2;
    float s[4] = {0.f, 0.f, 0.f, 0.f};
#pragma unroll
    for (int j = 0; j < 3; ++j) {
        int e = d_EOFV[v][j];
        ushort4 x = ((const ushort4*)E2c)[(((size_t)brel * 12 + e) * 16 + t) * 128 + c4];
        s[0] += b2f(x.x); s[1] += b2f(x.y); s[2] += b2f(x.z); s[3] += b2f(x.w);
    }
    ((ushort4*)nraw)[((((size_t)(b0 + brel)) * 4 + v) * 16 + t) * 128 + c4] =
        make_ushort4(f2b(s[0]), f2b(s[1]), f2b(s[2]), f2b(s[3]));
}

__global__ __launch_bounds__(256) void feat_mean_k(
    const unsigned short* __restrict__ q, unsigned short* __restrict__ feat)
{
    int i = blockIdx.x * 256 + threadIdx.x;
    if (i >= Bb * 128) return;
    int c4 = i & 127; int b = i >> 7;
    float s[4] = {0.f, 0.f, 0.f, 0.f};
#pragma unroll
    for (int v = 0; v < 4; ++v) {
        ushort4 x = ((const ushort4*)q)[(((size_t)b * 4 + v)) * 128 + c4];
        s[0] += b2f(x.x); s[1] += b2f(x.y); s[2] += b2f(x.z); s[3] += b2f(x.w);
    }
    ((ushort4*)feat)[(size_t)b * 128 + c4] = make_ushort4(
        f2b(0.25f * s[0]), f2b(0.25f * s[1]), f2b(0.25f * s[2]), f2b(0.25f * s[3]));
}

// final: out[m,n] = bf16 H2[m,:] @ fp32 cl_w3[:,n] + b3[n]
__global__ __launch_bounds__(256) void final_gemm_k(
    const unsigned short* __restrict__ H2, const float* __restrict__ W,
    const float* __restrict__ b, float* __restrict__ out)
{
    int i = blockIdx.x * 256 + threadIdx.x;
    if (i >= Bb * NCc) return;
    int n = i % NCc; int m = i / NCc;
    float s = b[n];
    for (int k = 0; k < 512; ++k)
        s += b2f(H2[(size_t)m * 512 + k]) * W[(size_t)k * NCc + n];
    out[i] = s;
}

__global__ __launch_bounds__(256) void copy_labels_k(
    const int* __restrict__ lab, float* __restrict__ out)
{
    int i = blockIdx.x * 256 + threadIdx.x;
    if (i < Bb) out[i] = (float)lab[i];
}

// ---------------- host-side helpers -----------------------------------------
static inline void gemm(hipStream_t s,
                        const unsigned short* A0, int Ka0, int K0,
                        const unsigned short* A1, int Ka1, int K1,
                        const unsigned short* WT, int Kw, int wtoff,
                        unsigned short* C, int M, int N,
                        const float* bias, int act, float* stats)
{
    dim3 g(N / 128, M / 128, 1);
    hipLaunchKernelGGL(gemm_bf16, g, dim3(256), 0, s,
                       A0, Ka0, K0, A1, Ka1, K1, WT, Kw, wtoff, C, M, N,
                       bias, act, stats, (float*)nullptr, K0 + K1);
}

static inline void bn_fin(hipStream_t s, const float* slot, const float* g,
                          const float* b, float* sc, int C, float cnt)
{
    hipLaunchKernelGGL(bn_finalize_k, dim3((C + 255) / 256), dim3(256), 0, s,
                       slot, g, b, sc, C, cnt);
}

static inline void bn_apply(hipStream_t s, unsigned short* X, long n, int C,
                            const float* sc, float premul, int act)
{
    long n4 = n / 4;
    hipLaunchKernelGGL(bn_apply_k, dim3((unsigned)((n4 + 255) / 256)), dim3(256), 0, s,
                       X, n4, C - 1, sc, premul, act);
}

static inline void transposeW(hipStream_t s, const float* W, unsigned short* WT, int K)
{
    int n = K * 512;
    hipLaunchKernelGGL(transpose_w_k, dim3((n + 255) / 256), dim3(256), 0, s, W, WT, K);
}

extern "C" void kernel_launch(void* const* d_in, const int* in_sizes, int n_in,
                              void* d_out, int out_size, void* d_ws, size_t ws_size,
                              hipStream_t stream)
{
    const int*   box_cat = (const int*)  d_in[1];
    const float* box_in  = (const float*)d_in[2];
    const int*   vlabel  = (const int*)  d_in[4];
    const float* emb     = (const float*)d_in[5];
    const float* c2f_w1  = (const float*)d_in[6];
    const float* c2f_g1  = (const float*)d_in[7];
    const float* c2f_b1  = (const float*)d_in[8];
    const float* c2f_w2  = (const float*)d_in[9];
    const float* c2f_g2  = (const float*)d_in[10];
    const float* c2f_b2  = (const float*)d_in[11];
    const float* fus_w   = (const float*)d_in[12];
    const float* fus_g   = (const float*)d_in[13];
    const float* fus_b   = (const float*)d_in[14];
    const float* m1_w1   = (const float*)d_in[15];
    const float* m1_b1   = (const float*)d_in[16];
    const float* m1_w2   = (const float*)d_in[17];
    const float* m1_b2   = (const float*)d_in[18];
    const float* m1_g    = (const float*)d_in[19];
    const float* m1_bb   = (const float*)d_in[20];
    const float* m2_w1   = (const float*)d_in[21];
    const float* m2_b1   = (const float*)d_in[22];
    const float* m2_w2   = (const float*)d_in[23];
    const float* m2_b2   = (const float*)d_in[24];
    const float* m2_g    = (const float*)d_in[25];
    const float* m2_bb   = (const float*)d_in[26];
    const float* t1_w1   = (const float*)d_in[27];
    const float* t1_b1   = (const float*)d_in[28];
    const float* t1_w2   = (const float*)d_in[29];
    const float* t1_b2   = (const float*)d_in[30];
    const float* t1_g    = (const float*)d_in[31];
    const float* t1_bb   = (const float*)d_in[32];
    const float* ps_w1   = (const float*)d_in[33];
    const float* ps_g1   = (const float*)d_in[34];
    const float* ps_b1   = (const float*)d_in[35];
    const float* ps_w2   = (const float*)d_in[36];
    const float* ps_g2   = (const float*)d_in[37];
    const float* ps_b2   = (const float*)d_in[38];
    const float* tb_w1   = (const float*)d_in[39];
    const float* tb_g1   = (const float*)d_in[40];
    const float* tb_b1   = (const float*)d_in[41];
    const float* tb_w2   = (const float*)d_in[42];
    const float* tb_g2   = (const float*)d_in[43];
    const float* tb_b2   = (const float*)d_in[44];
    const float* cl_w1   = (const float*)d_in[45];
    const float* cl_b1   = (const float*)d_in[46];
    const float* cl_w2   = (const float*)d_in[47];
    const float* cl_b2   = (const float*)d_in[48];
    const float* cl_w3   = (const float*)d_in[49];
    const float* cl_b3   = (const float*)d_in[50];

    float* out = (float*)d_out;

    // ---------------- workspace layout (bytes) ------------------------------
    char* base = (char*)d_ws;
    const size_t SZ_ACT = (size_t)NROW * 512 * 2;       // 32 MB
    unsigned short* A0v = (unsigned short*)(base);
    unsigned short* A1v = (unsigned short*)(base + SZ_ACT);
    char* Sreg = base + 2 * SZ_ACT;                     // 64 MB scratch region
    unsigned short* A2v = (unsigned short*)Sreg;        // 32 MB window in S
    // prep-phase aliases in S
    unsigned short* CE  = (unsigned short*)Sreg;                       // 16 MB
    unsigned short* Y1  = (unsigned short*)(Sreg + (size_t)NROW * 256 * 2);
    // edge-phase aliases in S
    unsigned short* Pc  = (unsigned short*)Sreg;                                   // 8 MB
    unsigned short* Qc  = (unsigned short*)(Sreg + (size_t)CROWS_N * 512 * 2);     // 8 MB
    unsigned short* EC1 = (unsigned short*)(Sreg + 2 * (size_t)CROWS_N * 512 * 2); // 24 MB
    unsigned short* EC2 = (unsigned short*)(Sreg + 2 * (size_t)CROWS_N * 512 * 2
                                                 + (size_t)CROWS_E * 512 * 2);     // 24 MB
    // tb1 split-K fp32 partials alias (8 x 2048 x 512 fp32 = 32 MB, in Sreg)
    float* Ppart = (float*)Sreg;
    char* wtb = Sreg + 2 * (size_t)CROWS_N * 512 * 2 + 2 * (size_t)CROWS_E * 512 * 2;
    // WT region
    unsigned short* wtp = (unsigned short*)wtb;
    size_t wo = 0;
    auto alloc_wt = [&](int K) { unsigned short* p = wtp + wo; wo += (size_t)K * 512; return p; };
    unsigned short* WTc2f2 = alloc_wt(256);
    unsigned short* WTfus  = alloc_wt(768);
    unsigned short* WTm1a  = alloc_wt(1024);
    unsigned short* WTm1b  = alloc_wt(512);
    unsigned short* WTm2a  = alloc_wt(512);
    unsigned short* WTm2b  = alloc_wt(512);
    unsigned short* WTt1a  = alloc_wt(1024);
    unsigned short* WTt1b  = alloc_wt(512);
    unsigned short* WTps1  = alloc_wt(512);
    unsigned short* WTps2  = alloc_wt(512);
    unsigned short* WTtb1  = alloc_wt(8192);
    unsigned short* WTtb2  = alloc_wt(512);
    unsigned short* WTcl1  = alloc_wt(512);
    unsigned short* WTcl2  = alloc_wt(512);
    float* X0f   = (float*)(wtp + wo);
    float* STATS = X0f + (size_t)NROW * 4;
    float* SCALE = STATS + 10 * 1024;

    auto slot = [&](int i) { return STATS + (size_t)i * 1024; };
    auto scsh = [&](int i) { return SCALE + (size_t)i * 1024; };

    // 0. zero stats + weight prep
    hipLaunchKernelGGL(zero_k, dim3((10 * 1024 + 255) / 256), dim3(256), 0, stream,
                       STATS, 10 * 1024);
    transposeW(stream, c2f_w2, WTc2f2, 256);
    transposeW(stream, fus_w,  WTfus,  768);
    transposeW(stream, m1_w1,  WTm1a,  1024);
    transposeW(stream, m1_w2,  WTm1b,  512);
    transposeW(stream, m2_w1,  WTm2a,  512);
    transposeW(stream, m2_w2,  WTm2b,  512);
    transposeW(stream, t1_w1,  WTt1a,  1024);
    transposeW(stream, t1_w2,  WTt1b,  512);
    transposeW(stream, ps_w1,  WTps1,  512);
    transposeW(stream, ps_w2,  WTps2,  512);
    transposeW(stream, tb_w1,  WTtb1,  8192);
    transposeW(stream, tb_w2,  WTtb2,  512);
    transposeW(stream, cl_w1,  WTcl1,  512);
    transposeW(stream, cl_w2,  WTcl2,  512);

    // 1. inputs
    hipLaunchKernelGGL(build_x0_k, dim3((NROW * 4 + 255) / 256), dim3(256), 0, stream,
                       box_in, X0f);
    hipLaunchKernelGGL(build_ce_k, dim3((NROW * 64 + 255) / 256), dim3(256), 0, stream,
                       box_cat, emb, CE);

    // 2. c2f layer 1 (K=4 fp32) -> Y1 [NROW,256]; BN+ReLU in place
    hipLaunchKernelGGL(smallk_gemm_k, dim3((NROW * 64 + 255) / 256), dim3(256), 0,
                       stream, X0f, c2f_w1, Y1);
    {
        int rpb = 256;
        dim3 g(256 / 64, (NROW + rpb - 1) / rpb);
        hipLaunchKernelGGL(colstats_k, g, dim3(64), 0, stream, Y1, NROW, 256, rpb,
                           slot(0));
    }
    bn_fin(stream, slot(0), c2f_g1, c2f_b1, scsh(0), 256, (float)NROW);
    bn_apply(stream, Y1, (long)NROW * 256, 256, scsh(0), 1.f, 1);

    // 3. c2f layer 2 -> A1 (stats fused); BN+ReLU
    gemm(stream, Y1, 256, 256, nullptr, 0, 0, WTc2f2, 256, 0, A1v, NROW, 512,
         nullptr, 0, slot(1));
    bn_fin(stream, slot(1), c2f_g2, c2f_b2, scsh(1), 512, (float)NROW);
    bn_apply(stream, A1v, (long)NROW * 512, 512, scsh(1), 1.f, 1);

    // 4. fusion dual-K -> A0 (BF), stats fused; BN+ReLU
    gemm(stream, A1v, 512, 512, CE, 256, 256, WTfus, 768, 0, A0v, NROW, 512,
         nullptr, 0, slot(2));
    bn_fin(stream, slot(2), fus_g, fus_b, scsh(2), 512, (float)NROW);
    bn_apply(stream, A0v, (long)NROW * 512, 512, scsh(2), 1.f, 1);   // BF in A0

    // 5-7. edge pipeline chunked; node sums -> A1; EC2 stats fused (slot 3)
    for (int c = 0; c < NCHUNK; ++c) {
        const unsigned short* BFc = A0v + (size_t)c * CROWS_N * 512;
        gemm(stream, BFc, 512, 512, nullptr, 0, 0, WTm1a, 1024, 0,   Pc, CROWS_N, 512,
             nullptr, 0, nullptr);
        gemm(stream, BFc, 512, 512, nullptr, 0, 0, WTm1a, 1024, 512, Qc, CROWS_N, 512,
             nullptr, 0, nullptr);
        hipLaunchKernelGGL(edge_gather_k, dim3((CROWS_E * 128 + 255) / 256), dim3(256),
                           0, stream, Pc, Qc, m1_b1, EC1);
        gemm(stream, EC1, 512, 512, nullptr, 0, 0, WTm1b, 512, 0, EC2, CROWS_E, 512,
             m1_b2, 2, slot(3));
        hipLaunchKernelGGL(edge_agg_k, dim3((CB * Vv * Tt * 128 + 255) / 256), dim3(256),
                           0, stream, EC2, A1v, c * CB);
    }
    bn_fin(stream, slot(3), m1_g, m1_bb, scsh(3), 512, (float)EROW);
    bn_apply(stream, A1v, (long)NROW * 512, 512, scsh(3), 1.f / 3.f, 0); // n in A1

    // 8. m2 MLP
    gemm(stream, A1v, 512, 512, nullptr, 0, 0, WTm2a, 512, 0, A2v, NROW, 512,
         m2_b1, 2, nullptr);
    gemm(stream, A2v, 512, 512, nullptr, 0, 0, WTm2b, 512, 0, A1v, NROW, 512,
         m2_b2, 2, slot(4));
    bn_fin(stream, slot(4), m2_g, m2_bb, scsh(4), 512, (float)NROW);
    bn_apply(stream, A1v, (long)NROW * 512, 512, scsh(4), 1.f, 0);   // n2 in A1

    // 9. t1 MLP on cat(n2, BF)
    gemm(stream, A1v, 512, 512, A0v, 512, 512, WTt1a, 1024, 0, A2v, NROW, 512,
         t1_b1, 2, nullptr);
    gemm(stream, A2v, 512, 512, nullptr, 0, 0, WTt1b, 512, 0, A1v, NROW, 512,
         t1_b2, 2, slot(5));
    bn_fin(stream, slot(5), t1_g, t1_bb, scsh(5), 512, (float)NROW);
    bn_apply(stream, A1v, (long)NROW * 512, 512, scsh(5), 1.f, 0);   // p in A1

    // 10. ps
    gemm(stream, A1v, 512, 512, nullptr, 0, 0, WTps1, 512, 0, A2v, NROW, 512,
         nullptr, 0, slot(6));
    bn_fin(stream, slot(6), ps_g1, ps_b1, scsh(6), 512, (float)NROW);
    bn_apply(stream, A2v, (long)NROW * 512, 512, scsh(6), 1.f, 1);

    gemm(stream, A2v, 512, 512, nullptr, 0, 0, WTps2, 512, 0, A0v, NROW, 512,
         nullptr, 0, slot(7));
    bn_fin(stream, slot(7), ps_g2, ps_b2, scsh(7), 512, (float)NROW);
    bn_apply(stream, A0v, (long)NROW * 512, 512, scsh(7), 1.f, 1);   // p_final in A0

    // 11. tb1 split-K=8 (A0 viewed [2048 x 8192]); partials in Sreg; combine -> A1
    {
        dim3 g(512 / 128, 2048 / 128, 8);
        hipLaunchKernelGGL(gemm_bf16, g, dim3(256), 0, stream,
                           A0v, 8192, 8192, (const unsigned short*)nullptr, 0, 0,
                           WTtb1, 8192, 0, A1v, 2048, 512,
                           (const float*)nullptr, 0, (float*)nullptr, Ppart, 1024);
        dim3 gc(512 / 128, 2048 / 128);
        hipLaunchKernelGGL(combine_k, gc, dim3(256), 0, stream,
                           Ppart, 8, 2048, 512, A1v, slot(8), 0);
    }
    bn_fin(stream, slot(8), tb_g1, tb_b1, scsh(8), 512, (float)(Bb * Vv));
    bn_apply(stream, A1v, (long)Bb * Vv * 512, 512, scsh(8), 1.f, 1);

    gemm(stream, A1v, 512, 512, nullptr, 0, 0, WTtb2, 512, 0, A2v, Bb * Vv, 512,
         nullptr, 0, slot(9));
    bn_fin(stream, slot(9), tb_g2, tb_b2, scsh(9), 512, (float)(Bb * Vv));
    bn_apply(stream, A2v, (long)Bb * Vv * 512, 512, scsh(9), 1.f, 1); // q2 in A2

    // 12. feat mean -> A0 (512x512)
    hipLaunchKernelGGL(feat_mean_k, dim3((Bb * 128 + 255) / 256), dim3(256), 0, stream,
                       A2v, A0v);

    // 13. classifier (no BN)
    gemm(stream, A0v, 512, 512, nullptr, 0, 0, WTcl1, 512, 0, A1v, Bb, 512,
         cl_b1, 1, nullptr);
    gemm(stream, A1v, 512, 512, nullptr, 0, 0, WTcl2, 512, 0, A2v, Bb, 512,
         cl_b2, 1, nullptr);
    hipLaunchKernelGGL(final_gemm_k, dim3((Bb * NCc + 255) / 256), dim3(256), 0, stream,
                       A2v, cl_w3, cl_b3, out);

    // 14. labels
    hipLaunchKernelGGL(copy_labels_k, dim3((Bb + 255) / 256), dim3(256), 0, stream,
                       vlabel, out + (size_t)Bb * NCc);
}

// Round 5
// 1730.569 us; speedup vs baseline: 4.7036x; 1.0168x over previous
//
#include <hip/hip_runtime.h>
#include <math.h>

#define EPS_ 1e-5f

static constexpr int Bb = 512, Vv = 4, Tt = 16, Dd = 512, NCc = 174;
static constexpr int NROW = Bb * Vv * Tt;      // 32768
static constexpr int EROW = Bb * 12 * Tt;      // 98304
static constexpr int CB = 128;                 // batches per edge chunk
static constexpr int NCHUNK = Bb / CB;         // 4
static constexpr int CROWS_N = CB * Vv * Tt;   // 8192
static constexpr int CROWS_E = CB * 12 * Tt;   // 24576

__constant__ int d_SEND[12] = {0,0,0,1,1,1,2,2,2,3,3,3};
__constant__ int d_RECV[12] = {1,2,3,0,2,3,0,1,3,0,1,2};
__constant__ int d_EOFV[4][3] = {{3,6,9},{0,7,10},{1,4,11},{2,5,8}};

typedef float f32x4 __attribute__((ext_vector_type(4)));
typedef short s16x8 __attribute__((ext_vector_type(8)));

static __device__ __forceinline__ float b2f(unsigned short u) {
    union { unsigned int i; float f; } x; x.i = ((unsigned int)u) << 16; return x.f;
}
static __device__ __forceinline__ unsigned short f2b(float f) {
    union { float f; unsigned int i; } x; x.f = f;
    unsigned int r = (x.i + 0x7fffu + ((x.i >> 16) & 1u)) >> 16;
    return (unsigned short)r;
}
static __device__ __forceinline__ float act_f(float v, int act) {
    if (act == 1) return fmaxf(v, 0.f);
    if (act == 2) return (v > 0.f) ? v : (expf(v) - 1.f);
    return v;
}

#define GL2LDS(g, l) __builtin_amdgcn_global_load_lds(                     \
    (__attribute__((address_space(1))) void*)(g),                          \
    (__attribute__((address_space(3))) void*)(l), 16, 0, 0)

// ================= MFMA bf16 GEMM (m97-style global_load_lds staging) =====
// C[M,N] = act( A@W + bias ), A bf16 row-major, W transposed WT[n][k]
// (row stride Kw, k offset wtoff). Dual-input A: k<K0 from A0, else A1.
// Fused column stats (sum/sumsq of the WRITTEN value) when stats!=nullptr.
// Split-K: grid.z slices of Ksl; fp32 partials to Cpart[z][M][N] (no act/stats).
// M,N % 128 == 0; K0,K1,Ksl % 32 == 0.
__global__ __launch_bounds__(256) void gemm_bf16(
    const unsigned short* __restrict__ A0, int Ka0, int K0,
    const unsigned short* __restrict__ A1, int Ka1, int K1,
    const unsigned short* __restrict__ WT, int Kw, int wtoff,
    unsigned short* __restrict__ C, int M, int N,
    const float* __restrict__ bias, int act,
    float* __restrict__ stats, float* __restrict__ Cpart, int Ksl)
{
    __shared__ __align__(16) unsigned short As[128 * 32];
    __shared__ __align__(16) unsigned short Bs[128 * 32];
    int tid = threadIdx.x;
    int lane = tid & 63, wave = tid >> 6;
    int wr = wave >> 1, wc = wave & 1;
    int rowBase = blockIdx.y * 128;
    int colBase = blockIdx.x * 128;
    int g = lane >> 4, r16 = lane & 15;
    int koff = blockIdx.z * Ksl;

    int srow = wave * 32 + (lane >> 2);   // wave*32 .. wave*32+15
    int scol = (lane & 3) * 8;            // 0,8,16,24 (bf16 elems)
    unsigned short* lA0 = As + (wave * 32) * 32;
    unsigned short* lA1 = As + (wave * 32 + 16) * 32;
    unsigned short* lB0 = Bs + (wave * 32) * 32;
    unsigned short* lB1 = Bs + (wave * 32 + 16) * 32;
    const unsigned short* wrow  = WT + (size_t)(colBase + srow) * Kw + wtoff + scol;
    const unsigned short* wrow2 = WT + (size_t)(colBase + srow + 16) * Kw + wtoff + scol;

    f32x4 acc[4][4];
#pragma unroll
    for (int i = 0; i < 4; ++i)
#pragma unroll
        for (int j = 0; j < 4; ++j) acc[i][j] = (f32x4){0.f, 0.f, 0.f, 0.f};

    for (int k0 = 0; k0 < Ksl; k0 += 32) {
        int kg = koff + k0;
        const unsigned short* Ap; int lda; int kc;
        if (kg < K0) { Ap = A0; lda = Ka0; kc = kg; }
        else         { Ap = A1; lda = Ka1; kc = kg - K0; }
        const unsigned short* ga = Ap + (size_t)(rowBase + srow) * lda + kc + scol;
        GL2LDS(ga, lA0);
        GL2LDS(ga + (size_t)16 * lda, lA1);
        GL2LDS(wrow + kg, lB0);
        GL2LDS(wrow2 + kg, lB1);
        __syncthreads();
        s16x8 af[4], bfv[4];
#pragma unroll
        for (int i = 0; i < 4; ++i)
            af[i] = *(const s16x8*)(As + (wr * 64 + i * 16 + r16) * 32 + g * 8);
#pragma unroll
        for (int j = 0; j < 4; ++j)
            bfv[j] = *(const s16x8*)(Bs + (wc * 64 + j * 16 + r16) * 32 + g * 8);
#pragma unroll
        for (int i = 0; i < 4; ++i)
#pragma unroll
            for (int j = 0; j < 4; ++j)
                acc[i][j] = __builtin_amdgcn_mfma_f32_16x16x32_bf16(
                    af[i], bfv[j], acc[i][j], 0, 0, 0);
        __syncthreads();
    }

    if (Cpart) {
#pragma unroll
        for (int j = 0; j < 4; ++j) {
            int col = colBase + wc * 64 + j * 16 + r16;
#pragma unroll
            for (int i = 0; i < 4; ++i) {
                int row0 = rowBase + wr * 64 + i * 16 + g * 4;
#pragma unroll
                for (int p = 0; p < 4; ++p)
                    Cpart[((size_t)blockIdx.z * M + row0 + p) * N + col] = acc[i][j][p];
            }
        }
        return;
    }

#pragma unroll
    for (int j = 0; j < 4; ++j) {
        int col = colBase + wc * 64 + j * 16 + r16;
        float bcol = bias ? bias[col] : 0.f;
        float ssum = 0.f, sqsum = 0.f;
#pragma unroll
        for (int i = 0; i < 4; ++i) {
            int row0 = rowBase + wr * 64 + i * 16 + g * 4;
#pragma unroll
            for (int p = 0; p < 4; ++p) {
                float v = acc[i][j][p] + bcol;
                v = act_f(v, act);
                C[(size_t)(row0 + p) * N + col] = f2b(v);
                ssum += v; sqsum += v * v;
            }
        }
        if (stats) {
            ssum  += __shfl_xor(ssum, 16);  ssum  += __shfl_xor(ssum, 32);
            sqsum += __shfl_xor(sqsum, 16); sqsum += __shfl_xor(sqsum, 32);
            if (g == 0) {
                atomicAdd(&stats[col], ssum);
                atomicAdd(&stats[512 + col], sqsum);
            }
        }
    }
}

// ---- split-K combine, parallel + vectorized --------------------------------
// C = act(sum_z P[z]) (bf16), fused stats. N == 512. grid (1, M/8), 256 thr.
__global__ __launch_bounds__(256) void combine_k(
    const float4* __restrict__ P, int S, int M,
    unsigned short* __restrict__ C, float* __restrict__ stats, int act)
{
    int col4 = threadIdx.x & 127;            // 128 float4 groups = 512 cols
    int rh = threadIdx.x >> 7;
    int rb = blockIdx.y * 8;
    float4 s4 = make_float4(0.f, 0.f, 0.f, 0.f);
    float4 q4 = make_float4(0.f, 0.f, 0.f, 0.f);
#pragma unroll
    for (int i = 0; i < 4; ++i) {
        int row = rb + rh + 2 * i;
        float4 v = make_float4(0.f, 0.f, 0.f, 0.f);
#pragma unroll
        for (int z = 0; z < 8; ++z) {
            float4 p = P[((size_t)z * M + row) * 128 + col4];
            v.x += p.x; v.y += p.y; v.z += p.z; v.w += p.w;
        }
        v.x = act_f(v.x, act); v.y = act_f(v.y, act);
        v.z = act_f(v.z, act); v.w = act_f(v.w, act);
        ((ushort4*)C)[(size_t)row * 128 + col4] =
            make_ushort4(f2b(v.x), f2b(v.y), f2b(v.z), f2b(v.w));
        s4.x += v.x; s4.y += v.y; s4.z += v.z; s4.w += v.w;
        q4.x += v.x * v.x; q4.y += v.y * v.y; q4.z += v.z * v.z; q4.w += v.w * v.w;
    }
    __shared__ float4 sb[256], qb[256];
    sb[threadIdx.x] = s4; qb[threadIdx.x] = q4;
    __syncthreads();
    if (threadIdx.x < 128) {
        float4 a = sb[threadIdx.x], b = sb[threadIdx.x + 128];
        float4 c = qb[threadIdx.x], d = qb[threadIdx.x + 128];
        int col = threadIdx.x * 4;
        atomicAdd(&stats[col + 0], a.x + b.x);
        atomicAdd(&stats[col + 1], a.y + b.y);
        atomicAdd(&stats[col + 2], a.z + b.z);
        atomicAdd(&stats[col + 3], a.w + b.w);
        atomicAdd(&stats[512 + col + 0], c.x + d.x);
        atomicAdd(&stats[512 + col + 1], c.y + d.y);
        atomicAdd(&stats[512 + col + 2], c.z + d.z);
        atomicAdd(&stats[512 + col + 3], c.w + d.w);
    }
}

// ---- batched weight convert+transpose: WT[n*K + k] = bf16(W[k*512 + n]) ----
#define NTD 13
struct TBatch {
    const float* src[NTD];
    unsigned short* dst[NTD];
    int K[NTD];
    long base[NTD + 1];
};
__global__ __launch_bounds__(256) void transpose_batch_k(TBatch tb, long total)
{
    long i = (long)blockIdx.x * 256 + threadIdx.x;
    if (i >= total) return;
    int d = 0;
#pragma unroll
    for (int j = 0; j < NTD; ++j) if (i >= tb.base[j + 1]) d = j + 1;
    long r = i - tb.base[d];
    int k = (int)(r >> 9), n = (int)(r & 511);
    tb.dst[d][(size_t)n * tb.K[d] + k] = f2b(tb.src[d][r]);
}

// fused P/Q transpose for m1_w1 [1024,512]:
// WTpq[n][k] (n<1024, k<512): n<512 -> W[k*512+n] ; n>=512 -> W[(512+k)*512+n-512]
__global__ __launch_bounds__(256) void transpose_pq_k(
    const float* __restrict__ W, unsigned short* __restrict__ WT)
{
    int i = blockIdx.x * 256 + threadIdx.x;
    if (i >= 512 * 1024) return;
    int k = i >> 10, n = i & 1023;
    float v = (n < 512) ? W[(size_t)k * 512 + n] : W[(size_t)(512 + k) * 512 + (n - 512)];
    WT[(size_t)n * 512 + k] = f2b(v);
}

// ---- column stats over bf16 matrix (only for the K=4 first layer) ----------
__global__ __launch_bounds__(64) void colstats_k(
    const unsigned short* __restrict__ X, int R, int C, int rpb,
    float* __restrict__ slot)
{
    int col = blockIdx.x * 64 + threadIdx.x;
    if (col >= C) return;
    int r0 = blockIdx.y * rpb;
    int r1 = r0 + rpb; if (r1 > R) r1 = R;
    float s = 0.f, sq = 0.f;
    for (int r = r0; r < r1; ++r) {
        float v = b2f(X[(size_t)r * C + col]);
        s += v; sq += v * v;
    }
    atomicAdd(&slot[col], s);
    atomicAdd(&slot[512 + col], sq);
}

// in-place BN finalize+apply: X = act( X*premul*scale[c] + shift[c] )
// scale/shift computed inline from raw sums (slot) + gamma/beta.
__global__ __launch_bounds__(256) void bn_apply_k(
    unsigned short* __restrict__ X, long n4, int cmask4,
    const float* __restrict__ slot, const float* __restrict__ gm,
    const float* __restrict__ bt, float cnt, float premul, int act)
{
    long i = (long)blockIdx.x * 256 + threadIdx.x;
    if (i >= n4) return;
    ushort4 x = ((ushort4*)X)[i];
    int c = ((int)(i & cmask4)) * 4;
    unsigned short o[4] = {x.x, x.y, x.z, x.w};
#pragma unroll
    for (int e = 0; e < 4; ++e) {
        float mean = slot[c + e] / cnt;
        float var = fmaxf(slot[512 + c + e] / cnt - mean * mean, 0.f);
        float sc = gm[c + e] * rsqrtf(var + EPS_);
        float sh = bt[c + e] - mean * sc;
        float v = b2f(o[e]) * premul;
        v = v * sc + sh;
        o[e] = f2b(act_f(v, act));
    }
    ((ushort4*)X)[i] = make_ushort4(o[0], o[1], o[2], o[3]);
}

// ---------------- misc ------------------------------------------------------
__global__ __launch_bounds__(256) void zero_k(float* p, int n)
{
    int i = blockIdx.x * 256 + threadIdx.x;
    if (i < n) p[i] = 0.f;
}

__global__ __launch_bounds__(256) void build_x0_k(
    const float* __restrict__ box, float* __restrict__ X0)
{
    int i = blockIdx.x * 256 + threadIdx.x;
    if (i >= NROW * 4) return;
    int c = i & 3; int r = i >> 2;
    int t = r & 15; int bv = r >> 4; int v = bv & 3; int b = bv >> 2;
    X0[i] = box[(((size_t)b * Tt + t) * Vv + v) * 4 + c];
}

// CE[(b*V+v)*T+t, c] bf16 ; 4 cols per thread
__global__ __launch_bounds__(256) void build_ce_k(
    const int* __restrict__ cats, const float* __restrict__ emb,
    unsigned short* __restrict__ CE)
{
    int i = blockIdx.x * 256 + threadIdx.x;
    if (i >= NROW * 64) return;
    int c4 = i & 63; int r = i >> 6;
    int t = r & 15; int bv = r >> 4; int v = bv & 3; int b = bv >> 2;
    int cat = cats[((size_t)b * Tt + t) * Vv + v];
    unsigned short o[4];
#pragma unroll
    for (int e = 0; e < 4; ++e)
        o[e] = (cat == 0) ? 0 : f2b(emb[cat * 256 + c4 * 4 + e]);
    ((ushort4*)CE)[(size_t)r * 64 + c4] = make_ushort4(o[0], o[1], o[2], o[3]);
}

// c2f layer-1: Y1[m, n4*4..] = X0f[m,0:4] @ W4[4,256]  (fp32 math, bf16 out)
__global__ __launch_bounds__(256) void smallk_gemm_k(
    const float* __restrict__ X0, const float* __restrict__ W4,
    unsigned short* __restrict__ Y1)
{
    int i = blockIdx.x * 256 + threadIdx.x;
    if (i >= NROW * 64) return;
    int n4 = i & 63; int m = i >> 6;
    float4 x = *(const float4*)(X0 + m * 4);
    unsigned short o[4];
#pragma unroll
    for (int e = 0; e < 4; ++e) {
        int n = n4 * 4 + e;
        float v = x.x * W4[n] + x.y * W4[256 + n] + x.z * W4[512 + n] + x.w * W4[768 + n];
        o[e] = f2b(v);
    }
    ((ushort4*)Y1)[(size_t)m * 64 + n4] = make_ushort4(o[0], o[1], o[2], o[3]);
}

// chunk edge gather from merged PQ[row][1024]:
// E[(brel*12+e)*16+t, c] = elu( PQ[send_row][c] + PQ[recv_row][512+c] + b1[c] )
__global__ __launch_bounds__(256) void edge_gather_k(
    const unsigned short* __restrict__ PQ,
    const float* __restrict__ b1, unsigned short* __restrict__ E)
{
    int i = blockIdx.x * 256 + threadIdx.x;
    if (i >= CROWS_E * 128) return;
    int c4 = i & 127; int m = i >> 7;
    int t = m & 15; int be = m >> 4; int e = be % 12; int brel = be / 12;
    int s = d_SEND[e], r = d_RECV[e];
    ushort4 p = ((const ushort4*)PQ)[(((size_t)brel * 4 + s) * 16 + t) * 256 + c4];
    ushort4 q = ((const ushort4*)PQ)[(((size_t)brel * 4 + r) * 16 + t) * 256 + 128 + c4];
    unsigned short pa[4] = {p.x, p.y, p.z, p.w}, qa[4] = {q.x, q.y, q.z, q.w}, o[4];
#pragma unroll
    for (int e2 = 0; e2 < 4; ++e2) {
        float v = b2f(pa[e2]) + b2f(qa[e2]) + b1[c4 * 4 + e2];
        o[e2] = f2b(act_f(v, 2));
    }
    ((ushort4*)E)[i] = make_ushort4(o[0], o[1], o[2], o[3]);
}

// chunk aggregation: nsum[(b0+brel, v, t), c] = sum over 3 incoming edges (bf16)
__global__ __launch_bounds__(256) void edge_agg_k(
    const unsigned short* __restrict__ E2c, unsigned short* __restrict__ nraw, int b0)
{
    int i = blockIdx.x * 256 + threadIdx.x;
    if (i >= CB * Vv * Tt * 128) return;
    int c4 = i & 127; int r = i >> 7;
    int t = r & 15; int r2 = r >> 4; int v = r2 & 3; int brel = r2 >> 2;
    float s[4] = {0.f, 0.f, 0.f, 0.f};
#pragma unroll
    for (int j = 0; j < 3; ++j) {
        int e = d_EOFV[v][j];
        ushort4 x = ((const ushort4*)E2c)[(((size_t)brel * 12 + e) * 16 + t) * 128 + c4];
        s[0] += b2f(x.x); s[1] += b2f(x.y); s[2] += b2f(x.z); s[3] += b2f(x.w);
    }
    ((ushort4*)nraw)[((((size_t)(b0 + brel)) * 4 + v) * 16 + t) * 128 + c4] =
        make_ushort4(f2b(s[0]), f2b(s[1]), f2b(s[2]), f2b(s[3]));
}

__global__ __launch_bounds__(256) void feat_mean_k(
    const unsigned short* __restrict__ q, unsigned short* __restrict__ feat)
{
    int i = blockIdx.x * 256 + threadIdx.x;
    if (i >= Bb * 128) return;
    int c4 = i & 127; int b = i >> 7;
    float s[4] = {0.f, 0.f, 0.f, 0.f};
#pragma unroll
    for (int v = 0; v < 4; ++v) {
        ushort4 x = ((const ushort4*)q)[(((size_t)b * 4 + v)) * 128 + c4];
        s[0] += b2f(x.x); s[1] += b2f(x.y); s[2] += b2f(x.z); s[3] += b2f(x.w);
    }
    ((ushort4*)feat)[(size_t)b * 128 + c4] = make_ushort4(
        f2b(0.25f * s[0]), f2b(0.25f * s[1]), f2b(0.25f * s[2]), f2b(0.25f * s[3]));
}

// final: out[m,n] = bf16 H2[m,:] @ fp32 cl_w3[:,n] + b3[n]
__global__ __launch_bounds__(256) void final_gemm_k(
    const unsigned short* __restrict__ H2, const float* __restrict__ W,
    const float* __restrict__ b, float* __restrict__ out)
{
    int i = blockIdx.x * 256 + threadIdx.x;
    if (i >= Bb * NCc) return;
    int n = i % NCc; int m = i / NCc;
    float s = b[n];
    for (int k = 0; k < 512; ++k)
        s += b2f(H2[(size_t)m * 512 + k]) * W[(size_t)k * NCc + n];
    out[i] = s;
}

__global__ __launch_bounds__(256) void copy_labels_k(
    const int* __restrict__ lab, float* __restrict__ out)
{
    int i = blockIdx.x * 256 + threadIdx.x;
    if (i < Bb) out[i] = (float)lab[i];
}

// ---------------- host-side helpers -----------------------------------------
static inline void gemm(hipStream_t s,
                        const unsigned short* A0, int Ka0, int K0,
                        const unsigned short* A1, int Ka1, int K1,
                        const unsigned short* WT, int Kw, int wtoff,
                        unsigned short* C, int M, int N,
                        const float* bias, int act, float* stats)
{
    dim3 g(N / 128, M / 128, 1);
    hipLaunchKernelGGL(gemm_bf16, g, dim3(256), 0, s,
                       A0, Ka0, K0, A1, Ka1, K1, WT, Kw, wtoff, C, M, N,
                       bias, act, stats, (float*)nullptr, K0 + K1);
}

static inline void bn_apply(hipStream_t s, unsigned short* X, long n, int C,
                            const float* slot, const float* gm, const float* bt,
                            float cnt, float premul, int act)
{
    long n4 = n / 4;
    hipLaunchKernelGGL(bn_apply_k, dim3((unsigned)((n4 + 255) / 256)), dim3(256), 0, s,
                       X, n4, C / 4 - 1, slot, gm, bt, cnt, premul, act);
}

extern "C" void kernel_launch(void* const* d_in, const int* in_sizes, int n_in,
                              void* d_out, int out_size, void* d_ws, size_t ws_size,
                              hipStream_t stream)
{
    const int*   box_cat = (const int*)  d_in[1];
    const float* box_in  = (const float*)d_in[2];
    const int*   vlabel  = (const int*)  d_in[4];
    const float* emb     = (const float*)d_in[5];
    const float* c2f_w1  = (const float*)d_in[6];
    const float* c2f_g1  = (const float*)d_in[7];
    const float* c2f_b1  = (const float*)d_in[8];
    const float* c2f_w2  = (const float*)d_in[9];
    const float* c2f_g2  = (const float*)d_in[10];
    const float* c2f_b2  = (const float*)d_in[11];
    const float* fus_w   = (const float*)d_in[12];
    const float* fus_g   = (const float*)d_in[13];
    const float* fus_b   = (const float*)d_in[14];
    const float* m1_w1   = (const float*)d_in[15];
    const float* m1_b1   = (const float*)d_in[16];
    const float* m1_w2   = (const float*)d_in[17];
    const float* m1_b2   = (const float*)d_in[18];
    const float* m1_g    = (const float*)d_in[19];
    const float* m1_bb   = (const float*)d_in[20];
    const float* m2_w1   = (const float*)d_in[21];
    const float* m2_b1   = (const float*)d_in[22];
    const float* m2_w2   = (const float*)d_in[23];
    const float* m2_b2   = (const float*)d_in[24];
    const float* m2_g    = (const float*)d_in[25];
    const float* m2_bb   = (const float*)d_in[26];
    const float* t1_w1   = (const float*)d_in[27];
    const float* t1_b1   = (const float*)d_in[28];
    const float* t1_w2   = (const float*)d_in[29];
    const float* t1_b2   = (const float*)d_in[30];
    const float* t1_g    = (const float*)d_in[31];
    const float* t1_bb   = (const float*)d_in[32];
    const float* ps_w1   = (const float*)d_in[33];
    const float* ps_g1   = (const float*)d_in[34];
    const float* ps_b1   = (const float*)d_in[35];
    const float* ps_w2   = (const float*)d_in[36];
    const float* ps_g2   = (const float*)d_in[37];
    const float* ps_b2   = (const float*)d_in[38];
    const float* tb_w1   = (const float*)d_in[39];
    const float* tb_g1   = (const float*)d_in[40];
    const float* tb_b1   = (const float*)d_in[41];
    const float* tb_w2   = (const float*)d_in[42];
    const float* tb_g2   = (const float*)d_in[43];
    const float* tb_b2   = (const float*)d_in[44];
    const float* cl_w1   = (const float*)d_in[45];
    const float* cl_b1   = (const float*)d_in[46];
    const float* cl_w2   = (const float*)d_in[47];
    const float* cl_b2   = (const float*)d_in[48];
    const float* cl_w3   = (const float*)d_in[49];
    const float* cl_b3   = (const float*)d_in[50];

    float* out = (float*)d_out;

    // ---------------- workspace layout (bytes) ------------------------------
    char* base = (char*)d_ws;
    const size_t SZ_ACT = (size_t)NROW * 512 * 2;       // 32 MB
    unsigned short* A0v = (unsigned short*)(base);
    unsigned short* A1v = (unsigned short*)(base + SZ_ACT);
    char* Sreg = base + 2 * SZ_ACT;                     // 64 MB scratch region
    unsigned short* A2v = (unsigned short*)Sreg;        // 32 MB window in S
    // prep-phase aliases in S
    unsigned short* CE  = (unsigned short*)Sreg;                       // 16 MB
    unsigned short* Y1  = (unsigned short*)(Sreg + (size_t)NROW * 256 * 2);
    // edge-phase aliases in S
    unsigned short* PQc = (unsigned short*)Sreg;                                   // 16 MB
    unsigned short* EC1 = (unsigned short*)(Sreg + (size_t)CROWS_N * 1024 * 2);    // 24 MB
    unsigned short* EC2 = (unsigned short*)(Sreg + (size_t)CROWS_N * 1024 * 2
                                                 + (size_t)CROWS_E * 512 * 2);     // 24 MB
    // tb1 split-K fp32 partials alias (8 x 2048 x 512 fp32 = 32 MB, in Sreg)
    float* Ppart = (float*)Sreg;
    char* wtb = Sreg + (size_t)CROWS_N * 1024 * 2 + 2 * (size_t)CROWS_E * 512 * 2;
    // WT region
    unsigned short* wtp = (unsigned short*)wtb;
    size_t wo = 0;
    auto alloc_wt = [&](int K) { unsigned short* p = wtp + wo; wo += (size_t)K * 512; return p; };
    unsigned short* WTc2f2 = alloc_wt(256);
    unsigned short* WTfus  = alloc_wt(768);
    unsigned short* WTpq   = alloc_wt(1024);   // m1_w1 fused P/Q layout [1024 n][512 k]
    unsigned short* WTm1b  = alloc_wt(512);
    unsigned short* WTm2a  = alloc_wt(512);
    unsigned short* WTm2b  = alloc_wt(512);
    unsigned short* WTt1a  = alloc_wt(1024);
    unsigned short* WTt1b  = alloc_wt(512);
    unsigned short* WTps1  = alloc_wt(512);
    unsigned short* WTps2  = alloc_wt(512);
    unsigned short* WTtb1  = alloc_wt(8192);
    unsigned short* WTtb2  = alloc_wt(512);
    unsigned short* WTcl1  = alloc_wt(512);
    unsigned short* WTcl2  = alloc_wt(512);
    float* X0f   = (float*)(wtp + wo);
    float* STATS = X0f + (size_t)NROW * 4;

    auto slot = [&](int i) { return STATS + (size_t)i * 1024; };

    // 0. zero stats + weight prep (batched transposes + fused PQ transpose)
    hipLaunchKernelGGL(zero_k, dim3((10 * 1024 + 255) / 256), dim3(256), 0, stream,
                       STATS, 10 * 1024);
    {
        TBatch tb;
        const float* srcs[NTD] = {c2f_w2, fus_w, m1_w2, m2_w1, m2_w2, t1_w1, t1_w2,
                                  ps_w1, ps_w2, tb_w1, tb_w2, cl_w1, cl_w2};
        unsigned short* dsts[NTD] = {WTc2f2, WTfus, WTm1b, WTm2a, WTm2b, WTt1a, WTt1b,
                                     WTps1, WTps2, WTtb1, WTtb2, WTcl1, WTcl2};
        int Ks[NTD] = {256, 768, 512, 512, 512, 1024, 512, 512, 512, 8192, 512, 512, 512};
        long acc = 0;
        for (int i = 0; i < NTD; ++i) {
            tb.src[i] = srcs[i]; tb.dst[i] = dsts[i]; tb.K[i] = Ks[i];
            tb.base[i] = acc; acc += (long)Ks[i] * 512;
        }
        tb.base[NTD] = acc;
        hipLaunchKernelGGL(transpose_batch_k, dim3((unsigned)((acc + 255) / 256)),
                           dim3(256), 0, stream, tb, acc);
    }
    hipLaunchKernelGGL(transpose_pq_k, dim3((512 * 1024 + 255) / 256), dim3(256), 0,
                       stream, m1_w1, WTpq);

    // 1. inputs
    hipLaunchKernelGGL(build_x0_k, dim3((NROW * 4 + 255) / 256), dim3(256), 0, stream,
                       box_in, X0f);
    hipLaunchKernelGGL(build_ce_k, dim3((NROW * 64 + 255) / 256), dim3(256), 0, stream,
                       box_cat, emb, CE);

    // 2. c2f layer 1 (K=4 fp32) -> Y1 [NROW,256]; BN+ReLU in place
    hipLaunchKernelGGL(smallk_gemm_k, dim3((NROW * 64 + 255) / 256), dim3(256), 0,
                       stream, X0f, c2f_w1, Y1);
    {
        int rpb = 256;
        dim3 g(256 / 64, (NROW + rpb - 1) / rpb);
        hipLaunchKernelGGL(colstats_k, g, dim3(64), 0, stream, Y1, NROW, 256, rpb,
                           slot(0));
    }
    bn_apply(stream, Y1, (long)NROW * 256, 256, slot(0), c2f_g1, c2f_b1,
             (float)NROW, 1.f, 1);

    // 3. c2f layer 2 -> A1 (stats fused); BN+ReLU
    gemm(stream, Y1, 256, 256, nullptr, 0, 0, WTc2f2, 256, 0, A1v, NROW, 512,
         nullptr, 0, slot(1));
    bn_apply(stream, A1v, (long)NROW * 512, 512, slot(1), c2f_g2, c2f_b2,
             (float)NROW, 1.f, 1);

    // 4. fusion dual-K -> A0 (BF), stats fused; BN+ReLU
    gemm(stream, A1v, 512, 512, CE, 256, 256, WTfus, 768, 0, A0v, NROW, 512,
         nullptr, 0, slot(2));
    bn_apply(stream, A0v, (long)NROW * 512, 512, slot(2), fus_g, fus_b,
             (float)NROW, 1.f, 1);                                    // BF in A0

    // 5-7. edge pipeline chunked; node sums -> A1; EC2 stats fused (slot 3)
    for (int c = 0; c < NCHUNK; ++c) {
        const unsigned short* BFc = A0v + (size_t)c * CROWS_N * 512;
        gemm(stream, BFc, 512, 512, nullptr, 0, 0, WTpq, 512, 0, PQc, CROWS_N, 1024,
             nullptr, 0, nullptr);
        hipLaunchKernelGGL(edge_gather_k, dim3((CROWS_E * 128 + 255) / 256), dim3(256),
                           0, stream, PQc, m1_b1, EC1);
        gemm(stream, EC1, 512, 512, nullptr, 0, 0, WTm1b, 512, 0, EC2, CROWS_E, 512,
             m1_b2, 2, slot(3));
        hipLaunchKernelGGL(edge_agg_k, dim3((CB * Vv * Tt * 128 + 255) / 256), dim3(256),
                           0, stream, EC2, A1v, c * CB);
    }
    bn_apply(stream, A1v, (long)NROW * 512, 512, slot(3), m1_g, m1_bb,
             (float)EROW, 1.f / 3.f, 0);                              // n in A1

    // 8. m2 MLP
    gemm(stream, A1v, 512, 512, nullptr, 0, 0, WTm2a, 512, 0, A2v, NROW, 512,
         m2_b1, 2, nullptr);
    gemm(stream, A2v, 512, 512, nullptr, 0, 0, WTm2b, 512, 0, A1v, NROW, 512,
         m2_b2, 2, slot(4));
    bn_apply(stream, A1v, (long)NROW * 512, 512, slot(4), m2_g, m2_bb,
             (float)NROW, 1.f, 0);                                    // n2 in A1

    // 9. t1 MLP on cat(n2, BF)
    gemm(stream, A1v, 512, 512, A0v, 512, 512, WTt1a, 1024, 0, A2v, NROW, 512,
         t1_b1, 2, nullptr);
    gemm(stream, A2v, 512, 512, nullptr, 0, 0, WTt1b, 512, 0, A1v, NROW, 512,
         t1_b2, 2, slot(5));
    bn_apply(stream, A1v, (long)NROW * 512, 512, slot(5), t1_g, t1_bb,
             (float)NROW, 1.f, 0);                                    // p in A1

    // 10. ps
    gemm(stream, A1v, 512, 512, nullptr, 0, 0, WTps1, 512, 0, A2v, NROW, 512,
         nullptr, 0, slot(6));
    bn_apply(stream, A2v, (long)NROW * 512, 512, slot(6), ps_g1, ps_b1,
             (float)NROW, 1.f, 1);

    gemm(stream, A2v, 512, 512, nullptr, 0, 0, WTps2, 512, 0, A0v, NROW, 512,
         nullptr, 0, slot(7));
    bn_apply(stream, A0v, (long)NROW * 512, 512, slot(7), ps_g2, ps_b2,
             (float)NROW, 1.f, 1);                                    // p_final in A0

    // 11. tb1 split-K=8 (A0 viewed [2048 x 8192]); partials in Sreg; combine -> A1
    {
        dim3 g(512 / 128, 2048 / 128, 8);
        hipLaunchKernelGGL(gemm_bf16, g, dim3(256), 0, stream,
                           A0v, 8192, 8192, (const unsigned short*)nullptr, 0, 0,
                           WTtb1, 8192, 0, A1v, 2048, 512,
                           (const float*)nullptr, 0, (float*)nullptr, Ppart, 1024);
        hipLaunchKernelGGL(combine_k, dim3(1, 2048 / 8), dim3(256), 0, stream,
                           (const float4*)Ppart, 8, 2048, A1v, slot(8), 0);
    }
    bn_apply(stream, A1v, (long)Bb * Vv * 512, 512, slot(8), tb_g1, tb_b1,
             (float)(Bb * Vv), 1.f, 1);

    gemm(stream, A1v, 512, 512, nullptr, 0, 0, WTtb2, 512, 0, A2v, Bb * Vv, 512,
         nullptr, 0, slot(9));
    bn_apply(stream, A2v, (long)Bb * Vv * 512, 512, slot(9), tb_g2, tb_b2,
             (float)(Bb * Vv), 1.f, 1);                               // q2 in A2

    // 12. feat mean -> A0 (512x512)
    hipLaunchKernelGGL(feat_mean_k, dim3((Bb * 128 + 255) / 256), dim3(256), 0, stream,
                       A2v, A0v);

    // 13. classifier (no BN)
    gemm(stream, A0v, 512, 512, nullptr, 0, 0, WTcl1, 512, 0, A1v, Bb, 512,
         cl_b1, 1, nullptr);
    gemm(stream, A1v, 512, 512, nullptr, 0, 0, WTcl2, 512, 0, A2v, Bb, 512,
         cl_b2, 1, nullptr);
    hipLaunchKernelGGL(final_gemm_k, dim3((Bb * NCc + 255) / 256), dim3(256), 0, stream,
                       A2v, cl_w3, cl_b3, out);

    // 14. labels
    hipLaunchKernelGGL(copy_labels_k, dim3((Bb + 255) / 256), dim3(256), 0, stream,
                       vlabel, out + (size_t)Bb * NCc);
}

// Round 6
// 1666.921 us; speedup vs baseline: 4.8832x; 1.0382x over previous
//
#include <hip/hip_runtime.h>
#include <math.h>

#define EPS_ 1e-5f

static constexpr int Bb = 512, Vv = 4, Tt = 16, Dd = 512, NCc = 174;
static constexpr int NROW = Bb * Vv * Tt;      // 32768
static constexpr int EROW = Bb * 12 * Tt;      // 98304
static constexpr int CB = 128;                 // batches per edge chunk
static constexpr int NCHUNK = Bb / CB;         // 4
static constexpr int CROWS_N = CB * Vv * Tt;   // 8192
static constexpr int CROWS_E = CB * 12 * Tt;   // 24576

__constant__ int d_SEND[12] = {0,0,0,1,1,1,2,2,2,3,3,3};
__constant__ int d_RECV[12] = {1,2,3,0,2,3,0,1,3,0,1,2};
__constant__ int d_EOFV[4][3] = {{3,6,9},{0,7,10},{1,4,11},{2,5,8}};

typedef float f32x4 __attribute__((ext_vector_type(4)));
typedef short s16x8 __attribute__((ext_vector_type(8)));

static __device__ __forceinline__ float b2f(unsigned short u) {
    union { unsigned int i; float f; } x; x.i = ((unsigned int)u) << 16; return x.f;
}
static __device__ __forceinline__ unsigned short f2b(float f) {
    union { float f; unsigned int i; } x; x.f = f;
    unsigned int r = (x.i + 0x7fffu + ((x.i >> 16) & 1u)) >> 16;
    return (unsigned short)r;
}
static __device__ __forceinline__ float act_f(float v, int act) {
    if (act == 1) return fmaxf(v, 0.f);
    if (act == 2) return (v > 0.f) ? v : (__expf(v) - 1.f);
    return v;
}

#define GL2LDS(g, l) __builtin_amdgcn_global_load_lds(                     \
    (__attribute__((address_space(1))) void*)(g),                          \
    (__attribute__((address_space(3))) void*)(l), 16, 0, 0)

// ================= MFMA bf16 GEMM (swapped operands, vector epilogue) =====
// C[M,N] = act( A@W + bias ), A bf16 row-major, W transposed WT[n][k]
// (row stride Kw, k offset wtoff). Dual-input A: k<K0 from A0, else A1.
// Operand swap: mfma(W-frag, X-frag) -> lane's 4 acc regs = 4 consecutive
// OUTPUT COLUMNS -> ushort4/float4 stores.
// Fused column stats (sum/sumsq of the WRITTEN value) when stats!=nullptr.
// Split-K: grid.z slices of Ksl; fp32 partials to Cpart[z][M][N].
// M,N % 128 == 0; K0,K1,Ksl % 32 == 0.
__global__ __launch_bounds__(256) void gemm_bf16(
    const unsigned short* __restrict__ A0, int Ka0, int K0,
    const unsigned short* __restrict__ A1, int Ka1, int K1,
    const unsigned short* __restrict__ WT, int Kw, int wtoff,
    unsigned short* __restrict__ C, int M, int N,
    const float* __restrict__ bias, int act,
    float* __restrict__ stats, float* __restrict__ Cpart, int Ksl)
{
    __shared__ __align__(16) unsigned short As[128 * 32];
    __shared__ __align__(16) unsigned short Bs[128 * 32];
    int tid = threadIdx.x;
    int lane = tid & 63, wave = tid >> 6;
    int wr = wave >> 1, wc = wave & 1;
    int rowBase = blockIdx.y * 128;
    int colBase = blockIdx.x * 128;
    int g = lane >> 4, r16 = lane & 15;
    int koff = blockIdx.z * Ksl;

    int srow = wave * 32 + (lane >> 2);   // wave*32 .. wave*32+15
    int scol = (lane & 3) * 8;            // 0,8,16,24 (bf16 elems)
    unsigned short* lA0 = As + (wave * 32) * 32;
    unsigned short* lA1 = As + (wave * 32 + 16) * 32;
    unsigned short* lB0 = Bs + (wave * 32) * 32;
    unsigned short* lB1 = Bs + (wave * 32 + 16) * 32;
    const unsigned short* wrow  = WT + (size_t)(colBase + srow) * Kw + wtoff + scol;
    const unsigned short* wrow2 = WT + (size_t)(colBase + srow + 16) * Kw + wtoff + scol;

    f32x4 acc[4][4];
#pragma unroll
    for (int i = 0; i < 4; ++i)
#pragma unroll
        for (int j = 0; j < 4; ++j) acc[i][j] = (f32x4){0.f, 0.f, 0.f, 0.f};

    for (int k0 = 0; k0 < Ksl; k0 += 32) {
        int kg = koff + k0;
        const unsigned short* Ap; int lda; int kc;
        if (kg < K0) { Ap = A0; lda = Ka0; kc = kg; }
        else         { Ap = A1; lda = Ka1; kc = kg - K0; }
        const unsigned short* ga = Ap + (size_t)(rowBase + srow) * lda + kc + scol;
        GL2LDS(ga, lA0);
        GL2LDS(ga + (size_t)16 * lda, lA1);
        GL2LDS(wrow + kg, lB0);
        GL2LDS(wrow2 + kg, lB1);
        __syncthreads();
        s16x8 xf[4], wf[4];
#pragma unroll
        for (int j = 0; j < 4; ++j)
            xf[j] = *(const s16x8*)(As + (wr * 64 + j * 16 + r16) * 32 + g * 8);
#pragma unroll
        for (int i = 0; i < 4; ++i)
            wf[i] = *(const s16x8*)(Bs + (wc * 64 + i * 16 + r16) * 32 + g * 8);
        // D = W^T-tile (A-op) x X-tile (B-op): acc[i][j] regs = 4 consec cols
#pragma unroll
        for (int i = 0; i < 4; ++i)
#pragma unroll
            for (int j = 0; j < 4; ++j)
                acc[i][j] = __builtin_amdgcn_mfma_f32_16x16x32_bf16(
                    wf[i], xf[j], acc[i][j], 0, 0, 0);
        __syncthreads();
    }

    if (Cpart) {
#pragma unroll
        for (int j = 0; j < 4; ++j) {
            int row = rowBase + wr * 64 + j * 16 + r16;
#pragma unroll
            for (int i = 0; i < 4; ++i) {
                int col0 = colBase + wc * 64 + i * 16 + g * 4;
                float4 v = make_float4(acc[i][j][0], acc[i][j][1],
                                       acc[i][j][2], acc[i][j][3]);
                *(float4*)&Cpart[((size_t)blockIdx.z * M + row) * N + col0] = v;
            }
        }
        return;
    }

#pragma unroll
    for (int i = 0; i < 4; ++i) {
        int col0 = colBase + wc * 64 + i * 16 + g * 4;
        float4 b4 = bias ? *(const float4*)(bias + col0)
                         : make_float4(0.f, 0.f, 0.f, 0.f);
        float s[4] = {0.f, 0.f, 0.f, 0.f}, q[4] = {0.f, 0.f, 0.f, 0.f};
#pragma unroll
        for (int j = 0; j < 4; ++j) {
            int row = rowBase + wr * 64 + j * 16 + r16;
            float v0 = act_f(acc[i][j][0] + b4.x, act);
            float v1 = act_f(acc[i][j][1] + b4.y, act);
            float v2 = act_f(acc[i][j][2] + b4.z, act);
            float v3 = act_f(acc[i][j][3] + b4.w, act);
            *(ushort4*)&C[(size_t)row * N + col0] =
                make_ushort4(f2b(v0), f2b(v1), f2b(v2), f2b(v3));
            s[0] += v0; s[1] += v1; s[2] += v2; s[3] += v3;
            q[0] += v0 * v0; q[1] += v1 * v1; q[2] += v2 * v2; q[3] += v3 * v3;
        }
        if (stats) {
#pragma unroll
            for (int p = 0; p < 4; ++p) {
#pragma unroll
                for (int d = 1; d < 16; d <<= 1) {
                    s[p] += __shfl_xor(s[p], d);
                    q[p] += __shfl_xor(q[p], d);
                }
            }
            if (r16 == 0) {
#pragma unroll
                for (int p = 0; p < 4; ++p) {
                    atomicAdd(&stats[col0 + p], s[p]);
                    atomicAdd(&stats[512 + col0 + p], q[p]);
                }
            }
        }
    }
}

// ---- split-K combine, parallel + vectorized --------------------------------
// C = act(sum_z P[z]) (bf16), fused stats. N == 512. grid (1, M/8), 256 thr.
__global__ __launch_bounds__(256) void combine_k(
    const float4* __restrict__ P, int S, int M,
    unsigned short* __restrict__ C, float* __restrict__ stats, int act)
{
    int col4 = threadIdx.x & 127;            // 128 float4 groups = 512 cols
    int rh = threadIdx.x >> 7;
    int rb = blockIdx.y * 8;
    float4 s4 = make_float4(0.f, 0.f, 0.f, 0.f);
    float4 q4 = make_float4(0.f, 0.f, 0.f, 0.f);
#pragma unroll
    for (int i = 0; i < 4; ++i) {
        int row = rb + rh + 2 * i;
        float4 v = make_float4(0.f, 0.f, 0.f, 0.f);
#pragma unroll
        for (int z = 0; z < 8; ++z) {
            float4 p = P[((size_t)z * M + row) * 128 + col4];
            v.x += p.x; v.y += p.y; v.z += p.z; v.w += p.w;
        }
        v.x = act_f(v.x, act); v.y = act_f(v.y, act);
        v.z = act_f(v.z, act); v.w = act_f(v.w, act);
        ((ushort4*)C)[(size_t)row * 128 + col4] =
            make_ushort4(f2b(v.x), f2b(v.y), f2b(v.z), f2b(v.w));
        s4.x += v.x; s4.y += v.y; s4.z += v.z; s4.w += v.w;
        q4.x += v.x * v.x; q4.y += v.y * v.y; q4.z += v.z * v.z; q4.w += v.w * v.w;
    }
    __shared__ float4 sb[256], qb[256];
    sb[threadIdx.x] = s4; qb[threadIdx.x] = q4;
    __syncthreads();
    if (threadIdx.x < 128) {
        float4 a = sb[threadIdx.x], b = sb[threadIdx.x + 128];
        float4 c = qb[threadIdx.x], d = qb[threadIdx.x + 128];
        int col = threadIdx.x * 4;
        atomicAdd(&stats[col + 0], a.x + b.x);
        atomicAdd(&stats[col + 1], a.y + b.y);
        atomicAdd(&stats[col + 2], a.z + b.z);
        atomicAdd(&stats[col + 3], a.w + b.w);
        atomicAdd(&stats[512 + col + 0], c.x + d.x);
        atomicAdd(&stats[512 + col + 1], c.y + d.y);
        atomicAdd(&stats[512 + col + 2], c.z + d.z);
        atomicAdd(&stats[512 + col + 3], c.w + d.w);
    }
}

// ---- batched weight convert+transpose: WT[n*K + k] = bf16(W[k*512 + n]) ----
#define NTD 13
struct TBatch {
    const float* src[NTD];
    unsigned short* dst[NTD];
    int K[NTD];
    long base[NTD + 1];
};
__global__ __launch_bounds__(256) void transpose_batch_k(TBatch tb, long total)
{
    long i = (long)blockIdx.x * 256 + threadIdx.x;
    if (i >= total) return;
    int d = 0;
#pragma unroll
    for (int j = 0; j < NTD; ++j) if (i >= tb.base[j + 1]) d = j + 1;
    long r = i - tb.base[d];
    int k = (int)(r >> 9), n = (int)(r & 511);
    tb.dst[d][(size_t)n * tb.K[d] + k] = f2b(tb.src[d][r]);
}

// fused P/Q transpose for m1_w1 [1024,512]:
// WTpq[n][k] (n<1024, k<512): n<512 -> W[k*512+n] ; n>=512 -> W[(512+k)*512+n-512]
__global__ __launch_bounds__(256) void transpose_pq_k(
    const float* __restrict__ W, unsigned short* __restrict__ WT)
{
    int i = blockIdx.x * 256 + threadIdx.x;
    if (i >= 512 * 1024) return;
    int k = i >> 10, n = i & 1023;
    float v = (n < 512) ? W[(size_t)k * 512 + n] : W[(size_t)(512 + k) * 512 + (n - 512)];
    WT[(size_t)n * 512 + k] = f2b(v);
}

// ---- column stats over bf16 matrix (only for the K=4 first layer) ----------
__global__ __launch_bounds__(64) void colstats_k(
    const unsigned short* __restrict__ X, int R, int C, int rpb,
    float* __restrict__ slot)
{
    int col = blockIdx.x * 64 + threadIdx.x;
    if (col >= C) return;
    int r0 = blockIdx.y * rpb;
    int r1 = r0 + rpb; if (r1 > R) r1 = R;
    float s = 0.f, sq = 0.f;
    for (int r = r0; r < r1; ++r) {
        float v = b2f(X[(size_t)r * C + col]);
        s += v; sq += v * v;
    }
    atomicAdd(&slot[col], s);
    atomicAdd(&slot[512 + col], sq);
}

// in-place BN finalize+apply: X = act( X*premul*scale[c] + shift[c] )
// scale/shift computed ONCE per block into LDS; grid-stride body.
__global__ __launch_bounds__(256) void bn_apply_k(
    unsigned short* __restrict__ X, long n4, int cmask4, int C,
    const float* __restrict__ slot, const float* __restrict__ gm,
    const float* __restrict__ bt, float inv_cnt, float premul, int act)
{
    __shared__ float sc_s[512], sh_s[512];
    for (int c = threadIdx.x; c < C; c += 256) {
        float mean = slot[c] * inv_cnt;
        float var = fmaxf(slot[512 + c] * inv_cnt - mean * mean, 0.f);
        float sc = gm[c] * rsqrtf(var + EPS_);
        sc_s[c] = sc * premul;
        sh_s[c] = bt[c] - mean * sc;
    }
    __syncthreads();
    long stride = (long)gridDim.x * 256;
    for (long i = (long)blockIdx.x * 256 + threadIdx.x; i < n4; i += stride) {
        ushort4 x = ((ushort4*)X)[i];
        int c = ((int)(i & cmask4)) * 4;
        unsigned short o[4] = {x.x, x.y, x.z, x.w};
#pragma unroll
        for (int e = 0; e < 4; ++e) {
            float v = b2f(o[e]) * sc_s[c + e] + sh_s[c + e];
            o[e] = f2b(act_f(v, act));
        }
        ((ushort4*)X)[i] = make_ushort4(o[0], o[1], o[2], o[3]);
    }
}

// ---------------- misc ------------------------------------------------------
__global__ __launch_bounds__(256) void zero_k(float* p, int n)
{
    int i = blockIdx.x * 256 + threadIdx.x;
    if (i < n) p[i] = 0.f;
}

__global__ __launch_bounds__(256) void build_x0_k(
    const float* __restrict__ box, float* __restrict__ X0)
{
    int i = blockIdx.x * 256 + threadIdx.x;
    if (i >= NROW * 4) return;
    int c = i & 3; int r = i >> 2;
    int t = r & 15; int bv = r >> 4; int v = bv & 3; int b = bv >> 2;
    X0[i] = box[(((size_t)b * Tt + t) * Vv + v) * 4 + c];
}

// CE[(b*V+v)*T+t, c] bf16 ; 4 cols per thread
__global__ __launch_bounds__(256) void build_ce_k(
    const int* __restrict__ cats, const float* __restrict__ emb,
    unsigned short* __restrict__ CE)
{
    int i = blockIdx.x * 256 + threadIdx.x;
    if (i >= NROW * 64) return;
    int c4 = i & 63; int r = i >> 6;
    int t = r & 15; int bv = r >> 4; int v = bv & 3; int b = bv >> 2;
    int cat = cats[((size_t)b * Tt + t) * Vv + v];
    unsigned short o[4];
#pragma unroll
    for (int e = 0; e < 4; ++e)
        o[e] = (cat == 0) ? 0 : f2b(emb[cat * 256 + c4 * 4 + e]);
    ((ushort4*)CE)[(size_t)r * 64 + c4] = make_ushort4(o[0], o[1], o[2], o[3]);
}

// c2f layer-1: Y1[m, n4*4..] = X0f[m,0:4] @ W4[4,256]  (fp32 math, bf16 out)
__global__ __launch_bounds__(256) void smallk_gemm_k(
    const float* __restrict__ X0, const float* __restrict__ W4,
    unsigned short* __restrict__ Y1)
{
    int i = blockIdx.x * 256 + threadIdx.x;
    if (i >= NROW * 64) return;
    int n4 = i & 63; int m = i >> 6;
    float4 x = *(const float4*)(X0 + m * 4);
    unsigned short o[4];
#pragma unroll
    for (int e = 0; e < 4; ++e) {
        int n = n4 * 4 + e;
        float v = x.x * W4[n] + x.y * W4[256 + n] + x.z * W4[512 + n] + x.w * W4[768 + n];
        o[e] = f2b(v);
    }
    ((ushort4*)Y1)[(size_t)m * 64 + n4] = make_ushort4(o[0], o[1], o[2], o[3]);
}

// chunk edge gather from merged PQ[row][1024]:
// E[(brel*12+e)*16+t, c] = elu( PQ[send_row][c] + PQ[recv_row][512+c] + b1[c] )
__global__ __launch_bounds__(256) void edge_gather_k(
    const unsigned short* __restrict__ PQ,
    const float* __restrict__ b1, unsigned short* __restrict__ E)
{
    int i = blockIdx.x * 256 + threadIdx.x;
    if (i >= CROWS_E * 128) return;
    int c4 = i & 127; int m = i >> 7;
    int t = m & 15; int be = m >> 4; int e = be % 12; int brel = be / 12;
    int s = d_SEND[e], r = d_RECV[e];
    ushort4 p = ((const ushort4*)PQ)[(((size_t)brel * 4 + s) * 16 + t) * 256 + c4];
    ushort4 q = ((const ushort4*)PQ)[(((size_t)brel * 4 + r) * 16 + t) * 256 + 128 + c4];
    unsigned short pa[4] = {p.x, p.y, p.z, p.w}, qa[4] = {q.x, q.y, q.z, q.w}, o[4];
#pragma unroll
    for (int e2 = 0; e2 < 4; ++e2) {
        float v = b2f(pa[e2]) + b2f(qa[e2]) + b1[c4 * 4 + e2];
        o[e2] = f2b(act_f(v, 2));
    }
    ((ushort4*)E)[i] = make_ushort4(o[0], o[1], o[2], o[3]);
}

// chunk aggregation: nsum[(b0+brel, v, t), c] = sum over 3 incoming edges (bf16)
__global__ __launch_bounds__(256) void edge_agg_k(
    const unsigned short* __restrict__ E2c, unsigned short* __restrict__ nraw, int b0)
{
    int i = blockIdx.x * 256 + threadIdx.x;
    if (i >= CB * Vv * Tt * 128) return;
    int c4 = i & 127; int r = i >> 7;
    int t = r & 15; int r2 = r >> 4; int v = r2 & 3; int brel = r2 >> 2;
    float s[4] = {0.f, 0.f, 0.f, 0.f};
#pragma unroll
    for (int j = 0; j < 3; ++j) {
        int e = d_EOFV[v][j];
        ushort4 x = ((const ushort4*)E2c)[(((size_t)brel * 12 + e) * 16 + t) * 128 + c4];
        s[0] += b2f(x.x); s[1] += b2f(x.y); s[2] += b2f(x.z); s[3] += b2f(x.w);
    }
    ((ushort4*)nraw)[((((size_t)(b0 + brel)) * 4 + v) * 16 + t) * 128 + c4] =
        make_ushort4(f2b(s[0]), f2b(s[1]), f2b(s[2]), f2b(s[3]));
}

__global__ __launch_bounds__(256) void feat_mean_k(
    const unsigned short* __restrict__ q, unsigned short* __restrict__ feat)
{
    int i = blockIdx.x * 256 + threadIdx.x;
    if (i >= Bb * 128) return;
    int c4 = i & 127; int b = i >> 7;
    float s[4] = {0.f, 0.f, 0.f, 0.f};
#pragma unroll
    for (int v = 0; v < 4; ++v) {
        ushort4 x = ((const ushort4*)q)[(((size_t)b * 4 + v)) * 128 + c4];
        s[0] += b2f(x.x); s[1] += b2f(x.y); s[2] += b2f(x.z); s[3] += b2f(x.w);
    }
    ((ushort4*)feat)[(size_t)b * 128 + c4] = make_ushort4(
        f2b(0.25f * s[0]), f2b(0.25f * s[1]), f2b(0.25f * s[2]), f2b(0.25f * s[3]));
}

// final: out[m,n] = bf16 H2[m,:] @ fp32 cl_w3[:,n] + b3[n]
__global__ __launch_bounds__(256) void final_gemm_k(
    const unsigned short* __restrict__ H2, const float* __restrict__ W,
    const float* __restrict__ b, float* __restrict__ out)
{
    int i = blockIdx.x * 256 + threadIdx.x;
    if (i >= Bb * NCc) return;
    int n = i % NCc; int m = i / NCc;
    float s = b[n];
    for (int k = 0; k < 512; ++k)
        s += b2f(H2[(size_t)m * 512 + k]) * W[(size_t)k * NCc + n];
    out[i] = s;
}

__global__ __launch_bounds__(256) void copy_labels_k(
    const int* __restrict__ lab, float* __restrict__ out)
{
    int i = blockIdx.x * 256 + threadIdx.x;
    if (i < Bb) out[i] = (float)lab[i];
}

// ---------------- host-side helpers -----------------------------------------
static inline void gemm(hipStream_t s,
                        const unsigned short* A0, int Ka0, int K0,
                        const unsigned short* A1, int Ka1, int K1,
                        const unsigned short* WT, int Kw, int wtoff,
                        unsigned short* C, int M, int N,
                        const float* bias, int act, float* stats)
{
    dim3 g(N / 128, M / 128, 1);
    hipLaunchKernelGGL(gemm_bf16, g, dim3(256), 0, s,
                       A0, Ka0, K0, A1, Ka1, K1, WT, Kw, wtoff, C, M, N,
                       bias, act, stats, (float*)nullptr, K0 + K1);
}

static inline void bn_apply(hipStream_t s, unsigned short* X, long n, int C,
                            const float* slot, const float* gm, const float* bt,
                            float cnt, float premul, int act)
{
    long n4 = n / 4;
    long nb = (n4 + 255) / 256;
    if (nb > 1024) nb = 1024;
    hipLaunchKernelGGL(bn_apply_k, dim3((unsigned)nb), dim3(256), 0, s,
                       X, n4, C / 4 - 1, C, slot, gm, bt, 1.f / cnt, premul, act);
}

extern "C" void kernel_launch(void* const* d_in, const int* in_sizes, int n_in,
                              void* d_out, int out_size, void* d_ws, size_t ws_size,
                              hipStream_t stream)
{
    const int*   box_cat = (const int*)  d_in[1];
    const float* box_in  = (const float*)d_in[2];
    const int*   vlabel  = (const int*)  d_in[4];
    const float* emb     = (const float*)d_in[5];
    const float* c2f_w1  = (const float*)d_in[6];
    const float* c2f_g1  = (const float*)d_in[7];
    const float* c2f_b1  = (const float*)d_in[8];
    const float* c2f_w2  = (const float*)d_in[9];
    const float* c2f_g2  = (const float*)d_in[10];
    const float* c2f_b2  = (const float*)d_in[11];
    const float* fus_w   = (const float*)d_in[12];
    const float* fus_g   = (const float*)d_in[13];
    const float* fus_b   = (const float*)d_in[14];
    const float* m1_w1   = (const float*)d_in[15];
    const float* m1_b1   = (const float*)d_in[16];
    const float* m1_w2   = (const float*)d_in[17];
    const float* m1_b2   = (const float*)d_in[18];
    const float* m1_g    = (const float*)d_in[19];
    const float* m1_bb   = (const float*)d_in[20];
    const float* m2_w1   = (const float*)d_in[21];
    const float* m2_b1   = (const float*)d_in[22];
    const float* m2_w2   = (const float*)d_in[23];
    const float* m2_b2   = (const float*)d_in[24];
    const float* m2_g    = (const float*)d_in[25];
    const float* m2_bb   = (const float*)d_in[26];
    const float* t1_w1   = (const float*)d_in[27];
    const float* t1_b1   = (const float*)d_in[28];
    const float* t1_w2   = (const float*)d_in[29];
    const float* t1_b2   = (const float*)d_in[30];
    const float* t1_g    = (const float*)d_in[31];
    const float* t1_bb   = (const float*)d_in[32];
    const float* ps_w1   = (const float*)d_in[33];
    const float* ps_g1   = (const float*)d_in[34];
    const float* ps_b1   = (const float*)d_in[35];
    const float* ps_w2   = (const float*)d_in[36];
    const float* ps_g2   = (const float*)d_in[37];
    const float* ps_b2   = (const float*)d_in[38];
    const float* tb_w1   = (const float*)d_in[39];
    const float* tb_g1   = (const float*)d_in[40];
    const float* tb_b1   = (const float*)d_in[41];
    const float* tb_w2   = (const float*)d_in[42];
    const float* tb_g2   = (const float*)d_in[43];
    const float* tb_b2   = (const float*)d_in[44];
    const float* cl_w1   = (const float*)d_in[45];
    const float* cl_b1   = (const float*)d_in[46];
    const float* cl_w2   = (const float*)d_in[47];
    const float* cl_b2   = (const float*)d_in[48];
    const float* cl_w3   = (const float*)d_in[49];
    const float* cl_b3   = (const float*)d_in[50];

    float* out = (float*)d_out;

    // ---------------- workspace layout (bytes) ------------------------------
    char* base = (char*)d_ws;
    const size_t SZ_ACT = (size_t)NROW * 512 * 2;       // 32 MB
    unsigned short* A0v = (unsigned short*)(base);
    unsigned short* A1v = (unsigned short*)(base + SZ_ACT);
    char* Sreg = base + 2 * SZ_ACT;                     // 64 MB scratch region
    unsigned short* A2v = (unsigned short*)Sreg;        // 32 MB window in S
    // prep-phase aliases in S
    unsigned short* CE  = (unsigned short*)Sreg;                       // 16 MB
    unsigned short* Y1  = (unsigned short*)(Sreg + (size_t)NROW * 256 * 2);
    // edge-phase aliases in S
    unsigned short* PQc = (unsigned short*)Sreg;                                   // 16 MB
    unsigned short* EC1 = (unsigned short*)(Sreg + (size_t)CROWS_N * 1024 * 2);    // 24 MB
    unsigned short* EC2 = (unsigned short*)(Sreg + (size_t)CROWS_N * 1024 * 2
                                                 + (size_t)CROWS_E * 512 * 2);     // 24 MB
    // tb1 split-K fp32 partials alias (8 x 2048 x 512 fp32 = 32 MB, in Sreg)
    float* Ppart = (float*)Sreg;
    char* wtb = Sreg + (size_t)CROWS_N * 1024 * 2 + 2 * (size_t)CROWS_E * 512 * 2;
    // WT region
    unsigned short* wtp = (unsigned short*)wtb;
    size_t wo = 0;
    auto alloc_wt = [&](int K) { unsigned short* p = wtp + wo; wo += (size_t)K * 512; return p; };
    unsigned short* WTc2f2 = alloc_wt(256);
    unsigned short* WTfus  = alloc_wt(768);
    unsigned short* WTpq   = alloc_wt(1024);   // m1_w1 fused P/Q layout [1024 n][512 k]
    unsigned short* WTm1b  = alloc_wt(512);
    unsigned short* WTm2a  = alloc_wt(512);
    unsigned short* WTm2b  = alloc_wt(512);
    unsigned short* WTt1a  = alloc_wt(1024);
    unsigned short* WTt1b  = alloc_wt(512);
    unsigned short* WTps1  = alloc_wt(512);
    unsigned short* WTps2  = alloc_wt(512);
    unsigned short* WTtb1  = alloc_wt(8192);
    unsigned short* WTtb2  = alloc_wt(512);
    unsigned short* WTcl1  = alloc_wt(512);
    unsigned short* WTcl2  = alloc_wt(512);
    float* X0f   = (float*)(wtp + wo);
    float* STATS = X0f + (size_t)NROW * 4;

    auto slot = [&](int i) { return STATS + (size_t)i * 1024; };

    // 0. zero stats + weight prep (batched transposes + fused PQ transpose)
    hipLaunchKernelGGL(zero_k, dim3((10 * 1024 + 255) / 256), dim3(256), 0, stream,
                       STATS, 10 * 1024);
    {
        TBatch tb;
        const float* srcs[NTD] = {c2f_w2, fus_w, m1_w2, m2_w1, m2_w2, t1_w1, t1_w2,
                                  ps_w1, ps_w2, tb_w1, tb_w2, cl_w1, cl_w2};
        unsigned short* dsts[NTD] = {WTc2f2, WTfus, WTm1b, WTm2a, WTm2b, WTt1a, WTt1b,
                                     WTps1, WTps2, WTtb1, WTtb2, WTcl1, WTcl2};
        int Ks[NTD] = {256, 768, 512, 512, 512, 1024, 512, 512, 512, 8192, 512, 512, 512};
        long acc = 0;
        for (int i = 0; i < NTD; ++i) {
            tb.src[i] = srcs[i]; tb.dst[i] = dsts[i]; tb.K[i] = Ks[i];
            tb.base[i] = acc; acc += (long)Ks[i] * 512;
        }
        tb.base[NTD] = acc;
        hipLaunchKernelGGL(transpose_batch_k, dim3((unsigned)((acc + 255) / 256)),
                           dim3(256), 0, stream, tb, acc);
    }
    hipLaunchKernelGGL(transpose_pq_k, dim3((512 * 1024 + 255) / 256), dim3(256), 0,
                       stream, m1_w1, WTpq);

    // 1. inputs
    hipLaunchKernelGGL(build_x0_k, dim3((NROW * 4 + 255) / 256), dim3(256), 0, stream,
                       box_in, X0f);
    hipLaunchKernelGGL(build_ce_k, dim3((NROW * 64 + 255) / 256), dim3(256), 0, stream,
                       box_cat, emb, CE);

    // 2. c2f layer 1 (K=4 fp32) -> Y1 [NROW,256]; BN+ReLU in place
    hipLaunchKernelGGL(smallk_gemm_k, dim3((NROW * 64 + 255) / 256), dim3(256), 0,
                       stream, X0f, c2f_w1, Y1);
    {
        int rpb = 256;
        dim3 g(256 / 64, (NROW + rpb - 1) / rpb);
        hipLaunchKernelGGL(colstats_k, g, dim3(64), 0, stream, Y1, NROW, 256, rpb,
                           slot(0));
    }
    bn_apply(stream, Y1, (long)NROW * 256, 256, slot(0), c2f_g1, c2f_b1,
             (float)NROW, 1.f, 1);

    // 3. c2f layer 2 -> A1 (stats fused); BN+ReLU
    gemm(stream, Y1, 256, 256, nullptr, 0, 0, WTc2f2, 256, 0, A1v, NROW, 512,
         nullptr, 0, slot(1));
    bn_apply(stream, A1v, (long)NROW * 512, 512, slot(1), c2f_g2, c2f_b2,
             (float)NROW, 1.f, 1);

    // 4. fusion dual-K -> A0 (BF), stats fused; BN+ReLU
    gemm(stream, A1v, 512, 512, CE, 256, 256, WTfus, 768, 0, A0v, NROW, 512,
         nullptr, 0, slot(2));
    bn_apply(stream, A0v, (long)NROW * 512, 512, slot(2), fus_g, fus_b,
             (float)NROW, 1.f, 1);                                    // BF in A0

    // 5-7. edge pipeline chunked; node sums -> A1; EC2 stats fused (slot 3)
    for (int c = 0; c < NCHUNK; ++c) {
        const unsigned short* BFc = A0v + (size_t)c * CROWS_N * 512;
        gemm(stream, BFc, 512, 512, nullptr, 0, 0, WTpq, 512, 0, PQc, CROWS_N, 1024,
             nullptr, 0, nullptr);
        hipLaunchKernelGGL(edge_gather_k, dim3((CROWS_E * 128 + 255) / 256), dim3(256),
                           0, stream, PQc, m1_b1, EC1);
        gemm(stream, EC1, 512, 512, nullptr, 0, 0, WTm1b, 512, 0, EC2, CROWS_E, 512,
             m1_b2, 2, slot(3));
        hipLaunchKernelGGL(edge_agg_k, dim3((CB * Vv * Tt * 128 + 255) / 256), dim3(256),
                           0, stream, EC2, A1v, c * CB);
    }
    bn_apply(stream, A1v, (long)NROW * 512, 512, slot(3), m1_g, m1_bb,
             (float)EROW, 1.f / 3.f, 0);                              // n in A1

    // 8. m2 MLP
    gemm(stream, A1v, 512, 512, nullptr, 0, 0, WTm2a, 512, 0, A2v, NROW, 512,
         m2_b1, 2, nullptr);
    gemm(stream, A2v, 512, 512, nullptr, 0, 0, WTm2b, 512, 0, A1v, NROW, 512,
         m2_b2, 2, slot(4));
    bn_apply(stream, A1v, (long)NROW * 512, 512, slot(4), m2_g, m2_bb,
             (float)NROW, 1.f, 0);                                    // n2 in A1

    // 9. t1 MLP on cat(n2, BF)
    gemm(stream, A1v, 512, 512, A0v, 512, 512, WTt1a, 1024, 0, A2v, NROW, 512,
         t1_b1, 2, nullptr);
    gemm(stream, A2v, 512, 512, nullptr, 0, 0, WTt1b, 512, 0, A1v, NROW, 512,
         t1_b2, 2, slot(5));
    bn_apply(stream, A1v, (long)NROW * 512, 512, slot(5), t1_g, t1_bb,
             (float)NROW, 1.f, 0);                                    // p in A1

    // 10. ps
    gemm(stream, A1v, 512, 512, nullptr, 0, 0, WTps1, 512, 0, A2v, NROW, 512,
         nullptr, 0, slot(6));
    bn_apply(stream, A2v, (long)NROW * 512, 512, slot(6), ps_g1, ps_b1,
             (float)NROW, 1.f, 1);

    gemm(stream, A2v, 512, 512, nullptr, 0, 0, WTps2, 512, 0, A0v, NROW, 512,
         nullptr, 0, slot(7));
    bn_apply(stream, A0v, (long)NROW * 512, 512, slot(7), ps_g2, ps_b2,
             (float)NROW, 1.f, 1);                                    // p_final in A0

    // 11. tb1 split-K=8 (A0 viewed [2048 x 8192]); partials in Sreg; combine -> A1
    {
        dim3 g(512 / 128, 2048 / 128, 8);
        hipLaunchKernelGGL(gemm_bf16, g, dim3(256), 0, stream,
                           A0v, 8192, 8192, (const unsigned short*)nullptr, 0, 0,
                           WTtb1, 8192, 0, A1v, 2048, 512,
                           (const float*)nullptr, 0, (float*)nullptr, Ppart, 1024);
        hipLaunchKernelGGL(combine_k, dim3(1, 2048 / 8), dim3(256), 0, stream,
                           (const float4*)Ppart, 8, 2048, A1v, slot(8), 0);
    }
    bn_apply(stream, A1v, (long)Bb * Vv * 512, 512, slot(8), tb_g1, tb_b1,
             (float)(Bb * Vv), 1.f, 1);

    gemm(stream, A1v, 512, 512, nullptr, 0, 0, WTtb2, 512, 0, A2v, Bb * Vv, 512,
         nullptr, 0, slot(9));
    bn_apply(stream, A2v, (long)Bb * Vv * 512, 512, slot(9), tb_g2, tb_b2,
             (float)(Bb * Vv), 1.f, 1);                               // q2 in A2

    // 12. feat mean -> A0 (512x512)
    hipLaunchKernelGGL(feat_mean_k, dim3((Bb * 128 + 255) / 256), dim3(256), 0, stream,
                       A2v, A0v);

    // 13. classifier (no BN)
    gemm(stream, A0v, 512, 512, nullptr, 0, 0, WTcl1, 512, 0, A1v, Bb, 512,
         cl_b1, 1, nullptr);
    gemm(stream, A1v, 512, 512, nullptr, 0, 0, WTcl2, 512, 0, A2v, Bb, 512,
         cl_b2, 1, nullptr);
    hipLaunchKernelGGL(final_gemm_k, dim3((Bb * NCc + 255) / 256), dim3(256), 0, stream,
                       A2v, cl_w3, cl_b3, out);

    // 14. labels
    hipLaunchKernelGGL(copy_labels_k, dim3((Bb + 255) / 256), dim3(256), 0, stream,
                       vlabel, out + (size_t)Bb * NCc);
}

// Round 7
// 1605.806 us; speedup vs baseline: 5.0691x; 1.0381x over previous
//
#include <hip/hip_runtime.h>
#include <math.h>

#define EPS_ 1e-5f

static constexpr int Bb = 512, Vv = 4, Tt = 16, Dd = 512, NCc = 174;
static constexpr int NROW = Bb * Vv * Tt;      // 32768
static constexpr int EROW = Bb * 12 * Tt;      // 98304
static constexpr int CB = 128;                 // batches per edge chunk
static constexpr int NCHUNK = Bb / CB;         // 4
static constexpr int CROWS_N = CB * Vv * Tt;   // 8192
static constexpr int CROWS_E = CB * 12 * Tt;   // 24576

__constant__ int d_SEND[12] = {0,0,0,1,1,1,2,2,2,3,3,3};
__constant__ int d_RECV[12] = {1,2,3,0,2,3,0,1,3,0,1,2};
__constant__ int d_EOFV[4][3] = {{3,6,9},{0,7,10},{1,4,11},{2,5,8}};

typedef float f32x4 __attribute__((ext_vector_type(4)));
typedef short s16x8 __attribute__((ext_vector_type(8)));

static __device__ __forceinline__ float b2f(unsigned short u) {
    union { unsigned int i; float f; } x; x.i = ((unsigned int)u) << 16; return x.f;
}
static __device__ __forceinline__ unsigned short f2b(float f) {
    union { float f; unsigned int i; } x; x.f = f;
    unsigned int r = (x.i + 0x7fffu + ((x.i >> 16) & 1u)) >> 16;
    return (unsigned short)r;
}
static __device__ __forceinline__ float act_f(float v, int act) {
    if (act == 1) return fmaxf(v, 0.f);
    if (act == 2) return (v > 0.f) ? v : (__expf(v) - 1.f);
    return v;
}

#define GL2LDS(g, l) __builtin_amdgcn_global_load_lds(                     \
    (__attribute__((address_space(1))) void*)(g),                          \
    (__attribute__((address_space(3))) void*)(l), 16, 0, 0)

#define CS_STRIDE 136   // shorts per epilogue LDS row (128 + 8 pad), 16B aligned

// ================= MFMA bf16 GEMM =========================================
// C[M,N] = act( A@W + bias ), A bf16 row-major, W transposed WT[n][k]
// (row stride Kw, k offset wtoff). Dual-input A: k<K0 from A0, else A1.
// Swapped operands: acc[i][j] regs = 4 consecutive output cols.
// 1D grid with XCD-aware swizzle: blocks sharing an A-row-panel get ids
// congruent mod 8 -> same XCD -> A fetched once per XCD (requires M/128 % 8 == 0).
// Epilogue staged through LDS for full-line coalesced global stores.
// Fused column stats when stats!=nullptr. Split-K via grid.z (fp32 partials).
__global__ __launch_bounds__(256) void gemm_bf16(
    const unsigned short* __restrict__ A0, int Ka0, int K0,
    const unsigned short* __restrict__ A1, int Ka1, int K1,
    const unsigned short* __restrict__ WT, int Kw, int wtoff,
    unsigned short* __restrict__ C, int M, int N,
    const float* __restrict__ bias, int act,
    float* __restrict__ stats, float* __restrict__ Cpart, int Ksl)
{
    __shared__ __align__(16) unsigned short SMEM[128 * CS_STRIDE]; // 34 KB
    unsigned short* As = SMEM;              // 128*32 = 8 KB (K-loop phase)
    unsigned short* Bs = SMEM + 128 * 32;   // 8 KB
    int tid = threadIdx.x;
    int lane = tid & 63, wave = tid >> 6;
    int wr = wave >> 1, wc = wave & 1;
    int g = lane >> 4, r16 = lane & 15;

    // ---- XCD swizzle decode ----
    int nct = N >> 7, nrt = M >> 7;
    int id = blockIdx.x, bx, by;
    if ((nrt & 7) == 0) {
        int grp = id / (nct * 8);
        int rem = id - grp * nct * 8;
        by = grp * 8 + (rem & 7);
        bx = rem >> 3;
    } else { bx = id % nct; by = id / nct; }
    int rowBase = by * 128;
    int colBase = bx * 128;
    int koff = blockIdx.z * Ksl;

    int srow = wave * 32 + (lane >> 2);
    int scol = (lane & 3) * 8;
    unsigned short* lA0 = As + (wave * 32) * 32;
    unsigned short* lA1 = As + (wave * 32 + 16) * 32;
    unsigned short* lB0 = Bs + (wave * 32) * 32;
    unsigned short* lB1 = Bs + (wave * 32 + 16) * 32;
    const unsigned short* wrow  = WT + (size_t)(colBase + srow) * Kw + wtoff + scol;
    const unsigned short* wrow2 = WT + (size_t)(colBase + srow + 16) * Kw + wtoff + scol;

    f32x4 acc[4][4];
#pragma unroll
    for (int i = 0; i < 4; ++i)
#pragma unroll
        for (int j = 0; j < 4; ++j) acc[i][j] = (f32x4){0.f, 0.f, 0.f, 0.f};

    for (int k0 = 0; k0 < Ksl; k0 += 32) {
        int kg = koff + k0;
        const unsigned short* Ap; int lda; int kc;
        if (kg < K0) { Ap = A0; lda = Ka0; kc = kg; }
        else         { Ap = A1; lda = Ka1; kc = kg - K0; }
        const unsigned short* ga = Ap + (size_t)(rowBase + srow) * lda + kc + scol;
        GL2LDS(ga, lA0);
        GL2LDS(ga + (size_t)16 * lda, lA1);
        GL2LDS(wrow + kg, lB0);
        GL2LDS(wrow2 + kg, lB1);
        __syncthreads();
        s16x8 xf[4], wf[4];
#pragma unroll
        for (int j = 0; j < 4; ++j)
            xf[j] = *(const s16x8*)(As + (wr * 64 + j * 16 + r16) * 32 + g * 8);
#pragma unroll
        for (int i = 0; i < 4; ++i)
            wf[i] = *(const s16x8*)(Bs + (wc * 64 + i * 16 + r16) * 32 + g * 8);
#pragma unroll
        for (int i = 0; i < 4; ++i)
#pragma unroll
            for (int j = 0; j < 4; ++j)
                acc[i][j] = __builtin_amdgcn_mfma_f32_16x16x32_bf16(
                    wf[i], xf[j], acc[i][j], 0, 0, 0);
        __syncthreads();
    }

    if (Cpart) {
        // split-K fp32 partials (combined later); direct stores
#pragma unroll
        for (int j = 0; j < 4; ++j) {
            int row = rowBase + wr * 64 + j * 16 + r16;
#pragma unroll
            for (int i = 0; i < 4; ++i) {
                int col0 = colBase + wc * 64 + i * 16 + g * 4;
                float4 v = make_float4(acc[i][j][0], acc[i][j][1],
                                       acc[i][j][2], acc[i][j][3]);
                *(float4*)&Cpart[((size_t)blockIdx.z * M + row) * N + col0] = v;
            }
        }
        return;
    }

    // ---- epilogue: act/bias -> Cs (LDS) + fused stats ----
#pragma unroll
    for (int i = 0; i < 4; ++i) {
        int lc0 = wc * 64 + i * 16 + g * 4;          // col within tile
        float4 b4 = bias ? *(const float4*)(bias + colBase + lc0)
                         : make_float4(0.f, 0.f, 0.f, 0.f);
        float s[4] = {0.f, 0.f, 0.f, 0.f}, q[4] = {0.f, 0.f, 0.f, 0.f};
#pragma unroll
        for (int j = 0; j < 4; ++j) {
            int lr = wr * 64 + j * 16 + r16;         // row within tile
            float v0 = act_f(acc[i][j][0] + b4.x, act);
            float v1 = act_f(acc[i][j][1] + b4.y, act);
            float v2 = act_f(acc[i][j][2] + b4.z, act);
            float v3 = act_f(acc[i][j][3] + b4.w, act);
            *(ushort4*)&SMEM[lr * CS_STRIDE + lc0] =
                make_ushort4(f2b(v0), f2b(v1), f2b(v2), f2b(v3));
            s[0] += v0; s[1] += v1; s[2] += v2; s[3] += v3;
            q[0] += v0 * v0; q[1] += v1 * v1; q[2] += v2 * v2; q[3] += v3 * v3;
        }
        if (stats) {
#pragma unroll
            for (int p = 0; p < 4; ++p) {
#pragma unroll
                for (int d = 1; d < 16; d <<= 1) {
                    s[p] += __shfl_xor(s[p], d);
                    q[p] += __shfl_xor(q[p], d);
                }
            }
            if (r16 == 0) {
#pragma unroll
                for (int p = 0; p < 4; ++p) {
                    atomicAdd(&stats[colBase + lc0 + p], s[p]);
                    atomicAdd(&stats[512 + colBase + lc0 + p], q[p]);
                }
            }
        }
    }
    __syncthreads();
    // coalesced copy-out: 4 lanes cover one 64B line; 2 passes of 64 rows
    {
        int qd = tid & 3;            // 16B quarter-of-64B
        int rr = tid >> 2;           // 0..63
#pragma unroll
        for (int pass = 0; pass < 2; ++pass) {
            int lr = pass * 64 + rr;
            size_t grow = (size_t)(rowBase + lr) * N + colBase;
#pragma unroll
            for (int u = 0; u < 4; ++u) {
                int cofs = u * 32 + qd * 8;
                uint4 v = *(const uint4*)(SMEM + lr * CS_STRIDE + cofs);
                *(uint4*)&C[grow + cofs] = v;
            }
        }
    }
}

// ---- split-K combine, parallel + vectorized --------------------------------
__global__ __launch_bounds__(256) void combine_k(
    const float4* __restrict__ P, int S, int M,
    unsigned short* __restrict__ C, float* __restrict__ stats, int act)
{
    int col4 = threadIdx.x & 127;
    int rh = threadIdx.x >> 7;
    int rb = blockIdx.y * 8;
    float4 s4 = make_float4(0.f, 0.f, 0.f, 0.f);
    float4 q4 = make_float4(0.f, 0.f, 0.f, 0.f);
#pragma unroll
    for (int i = 0; i < 4; ++i) {
        int row = rb + rh + 2 * i;
        float4 v = make_float4(0.f, 0.f, 0.f, 0.f);
#pragma unroll
        for (int z = 0; z < 8; ++z) {
            float4 p = P[((size_t)z * M + row) * 128 + col4];
            v.x += p.x; v.y += p.y; v.z += p.z; v.w += p.w;
        }
        v.x = act_f(v.x, act); v.y = act_f(v.y, act);
        v.z = act_f(v.z, act); v.w = act_f(v.w, act);
        ((ushort4*)C)[(size_t)row * 128 + col4] =
            make_ushort4(f2b(v.x), f2b(v.y), f2b(v.z), f2b(v.w));
        s4.x += v.x; s4.y += v.y; s4.z += v.z; s4.w += v.w;
        q4.x += v.x * v.x; q4.y += v.y * v.y; q4.z += v.z * v.z; q4.w += v.w * v.w;
    }
    __shared__ float4 sb[256], qb[256];
    sb[threadIdx.x] = s4; qb[threadIdx.x] = q4;
    __syncthreads();
    if (threadIdx.x < 128) {
        float4 a = sb[threadIdx.x], b = sb[threadIdx.x + 128];
        float4 c = qb[threadIdx.x], d = qb[threadIdx.x + 128];
        int col = threadIdx.x * 4;
        atomicAdd(&stats[col + 0], a.x + b.x);
        atomicAdd(&stats[col + 1], a.y + b.y);
        atomicAdd(&stats[col + 2], a.z + b.z);
        atomicAdd(&stats[col + 3], a.w + b.w);
        atomicAdd(&stats[512 + col + 0], c.x + d.x);
        atomicAdd(&stats[512 + col + 1], c.y + d.y);
        atomicAdd(&stats[512 + col + 2], c.z + d.z);
        atomicAdd(&stats[512 + col + 3], c.w + d.w);
    }
}

// ---- batched weight convert+transpose: WT[n*K + k] = bf16(W[k*512 + n]) ----
#define NTD 13
struct TBatch {
    const float* src[NTD];
    unsigned short* dst[NTD];
    int K[NTD];
    long base[NTD + 1];
};
__global__ __launch_bounds__(256) void transpose_batch_k(TBatch tb, long total)
{
    long i = (long)blockIdx.x * 256 + threadIdx.x;
    if (i >= total) return;
    int d = 0;
#pragma unroll
    for (int j = 0; j < NTD; ++j) if (i >= tb.base[j + 1]) d = j + 1;
    long r = i - tb.base[d];
    int k = (int)(r >> 9), n = (int)(r & 511);
    tb.dst[d][(size_t)n * tb.K[d] + k] = f2b(tb.src[d][r]);
}

// fused P/Q transpose for m1_w1 [1024,512]
__global__ __launch_bounds__(256) void transpose_pq_k(
    const float* __restrict__ W, unsigned short* __restrict__ WT)
{
    int i = blockIdx.x * 256 + threadIdx.x;
    if (i >= 512 * 1024) return;
    int k = i >> 10, n = i & 1023;
    float v = (n < 512) ? W[(size_t)k * 512 + n] : W[(size_t)(512 + k) * 512 + (n - 512)];
    WT[(size_t)n * 512 + k] = f2b(v);
}

// ---- column stats over bf16 matrix (only for the K=4 first layer) ----------
__global__ __launch_bounds__(64) void colstats_k(
    const unsigned short* __restrict__ X, int R, int C, int rpb,
    float* __restrict__ slot)
{
    int col = blockIdx.x * 64 + threadIdx.x;
    if (col >= C) return;
    int r0 = blockIdx.y * rpb;
    int r1 = r0 + rpb; if (r1 > R) r1 = R;
    float s = 0.f, sq = 0.f;
    for (int r = r0; r < r1; ++r) {
        float v = b2f(X[(size_t)r * C + col]);
        s += v; sq += v * v;
    }
    atomicAdd(&slot[col], s);
    atomicAdd(&slot[512 + col], sq);
}

// in-place BN finalize+apply; scale/shift once per block into LDS
__global__ __launch_bounds__(256) void bn_apply_k(
    unsigned short* __restrict__ X, long n4, int cmask4, int C,
    const float* __restrict__ slot, const float* __restrict__ gm,
    const float* __restrict__ bt, float inv_cnt, float premul, int act)
{
    __shared__ float sc_s[512], sh_s[512];
    for (int c = threadIdx.x; c < C; c += 256) {
        float mean = slot[c] * inv_cnt;
        float var = fmaxf(slot[512 + c] * inv_cnt - mean * mean, 0.f);
        float sc = gm[c] * rsqrtf(var + EPS_);
        sc_s[c] = sc * premul;
        sh_s[c] = bt[c] - mean * sc;
    }
    __syncthreads();
    long stride = (long)gridDim.x * 256;
    for (long i = (long)blockIdx.x * 256 + threadIdx.x; i < n4; i += stride) {
        ushort4 x = ((ushort4*)X)[i];
        int c = ((int)(i & cmask4)) * 4;
        unsigned short o[4] = {x.x, x.y, x.z, x.w};
#pragma unroll
        for (int e = 0; e < 4; ++e) {
            float v = b2f(o[e]) * sc_s[c + e] + sh_s[c + e];
            o[e] = f2b(act_f(v, act));
        }
        ((ushort4*)X)[i] = make_ushort4(o[0], o[1], o[2], o[3]);
    }
}

// ---------------- misc ------------------------------------------------------
__global__ __launch_bounds__(256) void zero_k(float* p, int n)
{
    int i = blockIdx.x * 256 + threadIdx.x;
    if (i < n) p[i] = 0.f;
}

__global__ __launch_bounds__(256) void build_x0_k(
    const float* __restrict__ box, float* __restrict__ X0)
{
    int i = blockIdx.x * 256 + threadIdx.x;
    if (i >= NROW * 4) return;
    int c = i & 3; int r = i >> 2;
    int t = r & 15; int bv = r >> 4; int v = bv & 3; int b = bv >> 2;
    X0[i] = box[(((size_t)b * Tt + t) * Vv + v) * 4 + c];
}

__global__ __launch_bounds__(256) void build_ce_k(
    const int* __restrict__ cats, const float* __restrict__ emb,
    unsigned short* __restrict__ CE)
{
    int i = blockIdx.x * 256 + threadIdx.x;
    if (i >= NROW * 64) return;
    int c4 = i & 63; int r = i >> 6;
    int t = r & 15; int bv = r >> 4; int v = bv & 3; int b = bv >> 2;
    int cat = cats[((size_t)b * Tt + t) * Vv + v];
    unsigned short o[4];
#pragma unroll
    for (int e = 0; e < 4; ++e)
        o[e] = (cat == 0) ? 0 : f2b(emb[cat * 256 + c4 * 4 + e]);
    ((ushort4*)CE)[(size_t)r * 64 + c4] = make_ushort4(o[0], o[1], o[2], o[3]);
}

__global__ __launch_bounds__(256) void smallk_gemm_k(
    const float* __restrict__ X0, const float* __restrict__ W4,
    unsigned short* __restrict__ Y1)
{
    int i = blockIdx.x * 256 + threadIdx.x;
    if (i >= NROW * 64) return;
    int n4 = i & 63; int m = i >> 6;
    float4 x = *(const float4*)(X0 + m * 4);
    unsigned short o[4];
#pragma unroll
    for (int e = 0; e < 4; ++e) {
        int n = n4 * 4 + e;
        float v = x.x * W4[n] + x.y * W4[256 + n] + x.z * W4[512 + n] + x.w * W4[768 + n];
        o[e] = f2b(v);
    }
    ((ushort4*)Y1)[(size_t)m * 64 + n4] = make_ushort4(o[0], o[1], o[2], o[3]);
}

__global__ __launch_bounds__(256) void edge_gather_k(
    const unsigned short* __restrict__ PQ,
    const float* __restrict__ b1, unsigned short* __restrict__ E)
{
    int i = blockIdx.x * 256 + threadIdx.x;
    if (i >= CROWS_E * 128) return;
    int c4 = i & 127; int m = i >> 7;
    int t = m & 15; int be = m >> 4; int e = be % 12; int brel = be / 12;
    int s = d_SEND[e], r = d_RECV[e];
    ushort4 p = ((const ushort4*)PQ)[(((size_t)brel * 4 + s) * 16 + t) * 256 + c4];
    ushort4 q = ((const ushort4*)PQ)[(((size_t)brel * 4 + r) * 16 + t) * 256 + 128 + c4];
    unsigned short pa[4] = {p.x, p.y, p.z, p.w}, qa[4] = {q.x, q.y, q.z, q.w}, o[4];
#pragma unroll
    for (int e2 = 0; e2 < 4; ++e2) {
        float v = b2f(pa[e2]) + b2f(qa[e2]) + b1[c4 * 4 + e2];
        o[e2] = f2b(act_f(v, 2));
    }
    ((ushort4*)E)[i] = make_ushort4(o[0], o[1], o[2], o[3]);
}

__global__ __launch_bounds__(256) void edge_agg_k(
    const unsigned short* __restrict__ E2c, unsigned short* __restrict__ nraw, int b0)
{
    int i = blockIdx.x * 256 + threadIdx.x;
    if (i >= CB * Vv * Tt * 128) return;
    int c4 = i & 127; int r = i >> 7;
    int t = r & 15; int r2 = r >> 4; int v = r2 & 3; int brel = r2 >> 2;
    float s[4] = {0.f, 0.f, 0.f, 0.f};
#pragma unroll
    for (int j = 0; j < 3; ++j) {
        int e = d_EOFV[v][j];
        ushort4 x = ((const ushort4*)E2c)[(((size_t)brel * 12 + e) * 16 + t) * 128 + c4];
        s[0] += b2f(x.x); s[1] += b2f(x.y); s[2] += b2f(x.z); s[3] += b2f(x.w);
    }
    ((ushort4*)nraw)[((((size_t)(b0 + brel)) * 4 + v) * 16 + t) * 128 + c4] =
        make_ushort4(f2b(s[0]), f2b(s[1]), f2b(s[2]), f2b(s[3]));
}

__global__ __launch_bounds__(256) void feat_mean_k(
    const unsigned short* __restrict__ q, unsigned short* __restrict__ feat)
{
    int i = blockIdx.x * 256 + threadIdx.x;
    if (i >= Bb * 128) return;
    int c4 = i & 127; int b = i >> 7;
    float s[4] = {0.f, 0.f, 0.f, 0.f};
#pragma unroll
    for (int v = 0; v < 4; ++v) {
        ushort4 x = ((const ushort4*)q)[(((size_t)b * 4 + v)) * 128 + c4];
        s[0] += b2f(x.x); s[1] += b2f(x.y); s[2] += b2f(x.z); s[3] += b2f(x.w);
    }
    ((ushort4*)feat)[(size_t)b * 128 + c4] = make_ushort4(
        f2b(0.25f * s[0]), f2b(0.25f * s[1]), f2b(0.25f * s[2]), f2b(0.25f * s[3]));
}

__global__ __launch_bounds__(256) void final_gemm_k(
    const unsigned short* __restrict__ H2, const float* __restrict__ W,
    const float* __restrict__ b, float* __restrict__ out)
{
    int i = blockIdx.x * 256 + threadIdx.x;
    if (i >= Bb * NCc) return;
    int n = i % NCc; int m = i / NCc;
    float s = b[n];
    for (int k = 0; k < 512; ++k)
        s += b2f(H2[(size_t)m * 512 + k]) * W[(size_t)k * NCc + n];
    out[i] = s;
}

__global__ __launch_bounds__(256) void copy_labels_k(
    const int* __restrict__ lab, float* __restrict__ out)
{
    int i = blockIdx.x * 256 + threadIdx.x;
    if (i < Bb) out[i] = (float)lab[i];
}

// ---------------- host-side helpers -----------------------------------------
static inline void gemm(hipStream_t s,
                        const unsigned short* A0, int Ka0, int K0,
                        const unsigned short* A1, int Ka1, int K1,
                        const unsigned short* WT, int Kw, int wtoff,
                        unsigned short* C, int M, int N,
                        const float* bias, int act, float* stats)
{
    dim3 g((N / 128) * (M / 128), 1, 1);
    hipLaunchKernelGGL(gemm_bf16, g, dim3(256), 0, s,
                       A0, Ka0, K0, A1, Ka1, K1, WT, Kw, wtoff, C, M, N,
                       bias, act, stats, (float*)nullptr, K0 + K1);
}

static inline void bn_apply(hipStream_t s, unsigned short* X, long n, int C,
                            const float* slot, const float* gm, const float* bt,
                            float cnt, float premul, int act)
{
    long n4 = n / 4;
    long nb = (n4 + 255) / 256;
    if (nb > 1024) nb = 1024;
    hipLaunchKernelGGL(bn_apply_k, dim3((unsigned)nb), dim3(256), 0, s,
                       X, n4, C / 4 - 1, C, slot, gm, bt, 1.f / cnt, premul, act);
}

extern "C" void kernel_launch(void* const* d_in, const int* in_sizes, int n_in,
                              void* d_out, int out_size, void* d_ws, size_t ws_size,
                              hipStream_t stream)
{
    const int*   box_cat = (const int*)  d_in[1];
    const float* box_in  = (const float*)d_in[2];
    const int*   vlabel  = (const int*)  d_in[4];
    const float* emb     = (const float*)d_in[5];
    const float* c2f_w1  = (const float*)d_in[6];
    const float* c2f_g1  = (const float*)d_in[7];
    const float* c2f_b1  = (const float*)d_in[8];
    const float* c2f_w2  = (const float*)d_in[9];
    const float* c2f_g2  = (const float*)d_in[10];
    const float* c2f_b2  = (const float*)d_in[11];
    const float* fus_w   = (const float*)d_in[12];
    const float* fus_g   = (const float*)d_in[13];
    const float* fus_b   = (const float*)d_in[14];
    const float* m1_w1   = (const float*)d_in[15];
    const float* m1_b1   = (const float*)d_in[16];
    const float* m1_w2   = (const float*)d_in[17];
    const float* m1_b2   = (const float*)d_in[18];
    const float* m1_g    = (const float*)d_in[19];
    const float* m1_bb   = (const float*)d_in[20];
    const float* m2_w1   = (const float*)d_in[21];
    const float* m2_b1   = (const float*)d_in[22];
    const float* m2_w2   = (const float*)d_in[23];
    const float* m2_b2   = (const float*)d_in[24];
    const float* m2_g    = (const float*)d_in[25];
    const float* m2_bb   = (const float*)d_in[26];
    const float* t1_w1   = (const float*)d_in[27];
    const float* t1_b1   = (const float*)d_in[28];
    const float* t1_w2   = (const float*)d_in[29];
    const float* t1_b2   = (const float*)d_in[30];
    const float* t1_g    = (const float*)d_in[31];
    const float* t1_bb   = (const float*)d_in[32];
    const float* ps_w1   = (const float*)d_in[33];
    const float* ps_g1   = (const float*)d_in[34];
    const float* ps_b1   = (const float*)d_in[35];
    const float* ps_w2   = (const float*)d_in[36];
    const float* ps_g2   = (const float*)d_in[37];
    const float* ps_b2   = (const float*)d_in[38];
    const float* tb_w1   = (const float*)d_in[39];
    const float* tb_g1   = (const float*)d_in[40];
    const float* tb_b1   = (const float*)d_in[41];
    const float* tb_w2   = (const float*)d_in[42];
    const float* tb_g2   = (const float*)d_in[43];
    const float* tb_b2   = (const float*)d_in[44];
    const float* cl_w1   = (const float*)d_in[45];
    const float* cl_b1   = (const float*)d_in[46];
    const float* cl_w2   = (const float*)d_in[47];
    const float* cl_b2   = (const float*)d_in[48];
    const float* cl_w3   = (const float*)d_in[49];
    const float* cl_b3   = (const float*)d_in[50];

    float* out = (float*)d_out;

    // ---------------- workspace layout (bytes) ------------------------------
    char* base = (char*)d_ws;
    const size_t SZ_ACT = (size_t)NROW * 512 * 2;       // 32 MB
    unsigned short* A0v = (unsigned short*)(base);
    unsigned short* A1v = (unsigned short*)(base + SZ_ACT);
    char* Sreg = base + 2 * SZ_ACT;                     // 64 MB scratch region
    unsigned short* A2v = (unsigned short*)Sreg;
    unsigned short* CE  = (unsigned short*)Sreg;
    unsigned short* Y1  = (unsigned short*)(Sreg + (size_t)NROW * 256 * 2);
    unsigned short* PQc = (unsigned short*)Sreg;
    unsigned short* EC1 = (unsigned short*)(Sreg + (size_t)CROWS_N * 1024 * 2);
    unsigned short* EC2 = (unsigned short*)(Sreg + (size_t)CROWS_N * 1024 * 2
                                                 + (size_t)CROWS_E * 512 * 2);
    float* Ppart = (float*)Sreg;
    char* wtb = Sreg + (size_t)CROWS_N * 1024 * 2 + 2 * (size_t)CROWS_E * 512 * 2;
    unsigned short* wtp = (unsigned short*)wtb;
    size_t wo = 0;
    auto alloc_wt = [&](int K) { unsigned short* p = wtp + wo; wo += (size_t)K * 512; return p; };
    unsigned short* WTc2f2 = alloc_wt(256);
    unsigned short* WTfus  = alloc_wt(768);
    unsigned short* WTpq   = alloc_wt(1024);
    unsigned short* WTm1b  = alloc_wt(512);
    unsigned short* WTm2a  = alloc_wt(512);
    unsigned short* WTm2b  = alloc_wt(512);
    unsigned short* WTt1a  = alloc_wt(1024);
    unsigned short* WTt1b  = alloc_wt(512);
    unsigned short* WTps1  = alloc_wt(512);
    unsigned short* WTps2  = alloc_wt(512);
    unsigned short* WTtb1  = alloc_wt(8192);
    unsigned short* WTtb2  = alloc_wt(512);
    unsigned short* WTcl1  = alloc_wt(512);
    unsigned short* WTcl2  = alloc_wt(512);
    float* X0f   = (float*)(wtp + wo);
    float* STATS = X0f + (size_t)NROW * 4;

    auto slot = [&](int i) { return STATS + (size_t)i * 1024; };

    // 0. zero stats + weight prep
    hipLaunchKernelGGL(zero_k, dim3((10 * 1024 + 255) / 256), dim3(256), 0, stream,
                       STATS, 10 * 1024);
    {
        TBatch tb;
        const float* srcs[NTD] = {c2f_w2, fus_w, m1_w2, m2_w1, m2_w2, t1_w1, t1_w2,
                                  ps_w1, ps_w2, tb_w1, tb_w2, cl_w1, cl_w2};
        unsigned short* dsts[NTD] = {WTc2f2, WTfus, WTm1b, WTm2a, WTm2b, WTt1a, WTt1b,
                                     WTps1, WTps2, WTtb1, WTtb2, WTcl1, WTcl2};
        int Ks[NTD] = {256, 768, 512, 512, 512, 1024, 512, 512, 512, 8192, 512, 512, 512};
        long acc = 0;
        for (int i = 0; i < NTD; ++i) {
            tb.src[i] = srcs[i]; tb.dst[i] = dsts[i]; tb.K[i] = Ks[i];
            tb.base[i] = acc; acc += (long)Ks[i] * 512;
        }
        tb.base[NTD] = acc;
        hipLaunchKernelGGL(transpose_batch_k, dim3((unsigned)((acc + 255) / 256)),
                           dim3(256), 0, stream, tb, acc);
    }
    hipLaunchKernelGGL(transpose_pq_k, dim3((512 * 1024 + 255) / 256), dim3(256), 0,
                       stream, m1_w1, WTpq);

    // 1. inputs
    hipLaunchKernelGGL(build_x0_k, dim3((NROW * 4 + 255) / 256), dim3(256), 0, stream,
                       box_in, X0f);
    hipLaunchKernelGGL(build_ce_k, dim3((NROW * 64 + 255) / 256), dim3(256), 0, stream,
                       box_cat, emb, CE);

    // 2. c2f layer 1 (K=4 fp32) -> Y1 [NROW,256]; BN+ReLU in place
    hipLaunchKernelGGL(smallk_gemm_k, dim3((NROW * 64 + 255) / 256), dim3(256), 0,
                       stream, X0f, c2f_w1, Y1);
    {
        int rpb = 256;
        dim3 g(256 / 64, (NROW + rpb - 1) / rpb);
        hipLaunchKernelGGL(colstats_k, g, dim3(64), 0, stream, Y1, NROW, 256, rpb,
                           slot(0));
    }
    bn_apply(stream, Y1, (long)NROW * 256, 256, slot(0), c2f_g1, c2f_b1,
             (float)NROW, 1.f, 1);

    // 3. c2f layer 2 -> A1 (stats fused); BN+ReLU
    gemm(stream, Y1, 256, 256, nullptr, 0, 0, WTc2f2, 256, 0, A1v, NROW, 512,
         nullptr, 0, slot(1));
    bn_apply(stream, A1v, (long)NROW * 512, 512, slot(1), c2f_g2, c2f_b2,
             (float)NROW, 1.f, 1);

    // 4. fusion dual-K -> A0 (BF), stats fused; BN+ReLU
    gemm(stream, A1v, 512, 512, CE, 256, 256, WTfus, 768, 0, A0v, NROW, 512,
         nullptr, 0, slot(2));
    bn_apply(stream, A0v, (long)NROW * 512, 512, slot(2), fus_g, fus_b,
             (float)NROW, 1.f, 1);                                    // BF in A0

    // 5-7. edge pipeline chunked; node sums -> A1; EC2 stats fused (slot 3)
    for (int c = 0; c < NCHUNK; ++c) {
        const unsigned short* BFc = A0v + (size_t)c * CROWS_N * 512;
        gemm(stream, BFc, 512, 512, nullptr, 0, 0, WTpq, 512, 0, PQc, CROWS_N, 1024,
             nullptr, 0, nullptr);
        hipLaunchKernelGGL(edge_gather_k, dim3((CROWS_E * 128 + 255) / 256), dim3(256),
                           0, stream, PQc, m1_b1, EC1);
        gemm(stream, EC1, 512, 512, nullptr, 0, 0, WTm1b, 512, 0, EC2, CROWS_E, 512,
             m1_b2, 2, slot(3));
        hipLaunchKernelGGL(edge_agg_k, dim3((CB * Vv * Tt * 128 + 255) / 256), dim3(256),
                           0, stream, EC2, A1v, c * CB);
    }
    bn_apply(stream, A1v, (long)NROW * 512, 512, slot(3), m1_g, m1_bb,
             (float)EROW, 1.f / 3.f, 0);                              // n in A1

    // 8. m2 MLP
    gemm(stream, A1v, 512, 512, nullptr, 0, 0, WTm2a, 512, 0, A2v, NROW, 512,
         m2_b1, 2, nullptr);
    gemm(stream, A2v, 512, 512, nullptr, 0, 0, WTm2b, 512, 0, A1v, NROW, 512,
         m2_b2, 2, slot(4));
    bn_apply(stream, A1v, (long)NROW * 512, 512, slot(4), m2_g, m2_bb,
             (float)NROW, 1.f, 0);                                    // n2 in A1

    // 9. t1 MLP on cat(n2, BF)
    gemm(stream, A1v, 512, 512, A0v, 512, 512, WTt1a, 1024, 0, A2v, NROW, 512,
         t1_b1, 2, nullptr);
    gemm(stream, A2v, 512, 512, nullptr, 0, 0, WTt1b, 512, 0, A1v, NROW, 512,
         t1_b2, 2, slot(5));
    bn_apply(stream, A1v, (long)NROW * 512, 512, slot(5), t1_g, t1_bb,
             (float)NROW, 1.f, 0);                                    // p in A1

    // 10. ps
    gemm(stream, A1v, 512, 512, nullptr, 0, 0, WTps1, 512, 0, A2v, NROW, 512,
         nullptr, 0, slot(6));
    bn_apply(stream, A2v, (long)NROW * 512, 512, slot(6), ps_g1, ps_b1,
             (float)NROW, 1.f, 1);

    gemm(stream, A2v, 512, 512, nullptr, 0, 0, WTps2, 512, 0, A0v, NROW, 512,
         nullptr, 0, slot(7));
    bn_apply(stream, A0v, (long)NROW * 512, 512, slot(7), ps_g2, ps_b2,
             (float)NROW, 1.f, 1);                                    // p_final in A0

    // 11. tb1 split-K=8 (A0 viewed [2048 x 8192]); partials; combine -> A1
    {
        dim3 g((512 / 128) * (2048 / 128), 1, 8);
        hipLaunchKernelGGL(gemm_bf16, g, dim3(256), 0, stream,
                           A0v, 8192, 8192, (const unsigned short*)nullptr, 0, 0,
                           WTtb1, 8192, 0, A1v, 2048, 512,
                           (const float*)nullptr, 0, (float*)nullptr, Ppart, 1024);
        hipLaunchKernelGGL(combine_k, dim3(1, 2048 / 8), dim3(256), 0, stream,
                           (const float4*)Ppart, 8, 2048, A1v, slot(8), 0);
    }
    bn_apply(stream, A1v, (long)Bb * Vv * 512, 512, slot(8), tb_g1, tb_b1,
             (float)(Bb * Vv), 1.f, 1);

    gemm(stream, A1v, 512, 512, nullptr, 0, 0, WTtb2, 512, 0, A2v, Bb * Vv, 512,
         nullptr, 0, slot(9));
    bn_apply(stream, A2v, (long)Bb * Vv * 512, 512, slot(9), tb_g2, tb_b2,
             (float)(Bb * Vv), 1.f, 1);                               // q2 in A2

    // 12. feat mean -> A0 (512x512)
    hipLaunchKernelGGL(feat_mean_k, dim3((Bb * 128 + 255) / 256), dim3(256), 0, stream,
                       A2v, A0v);

    // 13. classifier (no BN)
    gemm(stream, A0v, 512, 512, nullptr, 0, 0, WTcl1, 512, 0, A1v, Bb, 512,
         cl_b1, 1, nullptr);
    gemm(stream, A1v, 512, 512, nullptr, 0, 0, WTcl2, 512, 0, A2v, Bb, 512,
         cl_b2, 1, nullptr);
    hipLaunchKernelGGL(final_gemm_k, dim3((Bb * NCc + 255) / 256), dim3(256), 0, stream,
                       A2v, cl_w3, cl_b3, out);

    // 14. labels
    hipLaunchKernelGGL(copy_labels_k, dim3((Bb + 255) / 256), dim3(256), 0, stream,
                       vlabel, out + (size_t)Bb * NCc);
}